// Round 1
// baseline (689.523 us; speedup 1.0000x reference)
//
#include <hip/hip_runtime.h>

#define N_NODES 50000
#define N_EDGES 1600000
#define SCAN_PAD 50176   // 49 * 1024

// ---------------- GEMM: H = X @ W   (X [n,128], W [128,128], H [n,128]) ----
__global__ __launch_bounds__(256) void gemm_x128(const float* __restrict__ X,
                                                 const float* __restrict__ W,
                                                 float* __restrict__ H, int nrows) {
    __shared__ float Wl[128 * 128];   // 64 KB
    __shared__ float xs[16][128];     // 8 KB
    int t = threadIdx.x;
    for (int i = t; i < 128 * 128; i += 256) Wl[i] = W[i];
    int lane32 = t & 31, rgrp = t >> 5;      // rgrp 0..7
    int c0 = lane32 * 4;
    for (int row0 = blockIdx.x * 16; row0 < nrows; row0 += gridDim.x * 16) {
        __syncthreads();   // covers W on first pass, xs-reuse on later passes
        for (int i = t; i < 2048; i += 256) {
            int rr = row0 + (i >> 7);
            xs[i >> 7][i & 127] = (rr < nrows) ? X[rr * 128 + (i & 127)] : 0.f;
        }
        __syncthreads();
        float4 a0 = make_float4(0, 0, 0, 0), a1 = make_float4(0, 0, 0, 0);
        #pragma unroll 4
        for (int k = 0; k < 128; ++k) {
            float4 w4 = *reinterpret_cast<const float4*>(&Wl[k * 128 + c0]);
            float x0 = xs[rgrp][k], x1 = xs[rgrp + 8][k];
            a0.x += x0 * w4.x; a0.y += x0 * w4.y; a0.z += x0 * w4.z; a0.w += x0 * w4.w;
            a1.x += x1 * w4.x; a1.y += x1 * w4.y; a1.z += x1 * w4.z; a1.w += x1 * w4.w;
        }
        int r0 = row0 + rgrp, r1 = r0 + 8;
        if (r0 < nrows) *reinterpret_cast<float4*>(&H[r0 * 128 + c0]) = a0;
        if (r1 < nrows) *reinterpret_cast<float4*>(&H[r1 * 128 + c0]) = a1;
    }
}

// ---------------- attention scores: a_s[n,h] = <h[n,h,:], att_src[h,:]> ----
__global__ __launch_bounds__(128) void attn_scores(const float* __restrict__ H,
                                                   const float* __restrict__ att_s,
                                                   const float* __restrict__ att_d,
                                                   float* __restrict__ as_out,
                                                   float* __restrict__ ad_out, int n) {
    int nid = blockIdx.x;
    if (nid >= n) return;
    int c = threadIdx.x;            // 0..127
    float hv = H[nid * 128 + c];
    int head = c >> 5, f = c & 31;
    float vs = hv * att_s[head * 32 + f];
    float vd = hv * att_d[head * 32 + f];
    #pragma unroll
    for (int m = 16; m >= 1; m >>= 1) {
        vs += __shfl_xor(vs, m);
        vd += __shfl_xor(vd, m);
    }
    if (f == 0) {
        as_out[nid * 4 + head] = vs;
        ad_out[nid * 4 + head] = vd;
    }
}

// ---------------- counting sort of edges by dst ----------------------------
__global__ __launch_bounds__(256) void edge_hist(const int* __restrict__ dst,
                                                 int* __restrict__ deg, int E) {
    int e = blockIdx.x * 256 + threadIdx.x;
    if (e < E) atomicAdd(&deg[dst[e]], 1);
}

__global__ __launch_bounds__(1024) void scan_block(const int* __restrict__ deg,
                                                   int* __restrict__ excl,
                                                   int* __restrict__ bsum, int n) {
    __shared__ int sh[1024];
    int g = blockIdx.x * 1024 + threadIdx.x;
    int v = (g < n) ? deg[g] : 0;
    sh[threadIdx.x] = v;
    __syncthreads();
    for (int off = 1; off < 1024; off <<= 1) {
        int tv = (threadIdx.x >= off) ? sh[threadIdx.x - off] : 0;
        __syncthreads();
        sh[threadIdx.x] += tv;
        __syncthreads();
    }
    if (g < n) excl[g] = sh[threadIdx.x] - v;   // exclusive within block
    if (threadIdx.x == 1023) bsum[blockIdx.x] = sh[1023];
}

__global__ void scan_bsums(int* bsum, int nb) {
    if (blockIdx.x == 0 && threadIdx.x == 0) {
        int acc = 0;
        for (int i = 0; i < nb; ++i) { int v = bsum[i]; bsum[i] = acc; acc += v; }
    }
}

__global__ __launch_bounds__(256) void add_offsets(const int* __restrict__ excl,
                                                   const int* __restrict__ bsum,
                                                   int* __restrict__ off,
                                                   int* __restrict__ cursor,
                                                   int n, int E) {
    int g = blockIdx.x * 256 + threadIdx.x;
    if (g < n) {
        int v = excl[g] + bsum[g >> 10];
        off[g] = v;
        cursor[g] = v;
    }
    if (g == n) off[n] = E;
}

__global__ __launch_bounds__(256) void edge_scatter(const int* __restrict__ src,
                                                    const int* __restrict__ dst,
                                                    int* __restrict__ cursor,
                                                    int* __restrict__ sorted_src, int E) {
    int e = blockIdx.x * 256 + threadIdx.x;
    if (e < E) {
        int d = dst[e];
        int p = atomicAdd(&cursor[d], 1);
        sorted_src[p] = src[e];
    }
}

// ---------------- fused softmax + aggregate: one wave per dst node ---------
__global__ __launch_bounds__(256) void gat_aggregate(const float* __restrict__ H,
                                                     const int* __restrict__ off,
                                                     const int* __restrict__ sorted_src,
                                                     const float* __restrict__ as_in,
                                                     const float* __restrict__ ad_in,
                                                     const float* __restrict__ bias,
                                                     float* __restrict__ OUT,
                                                     int n, int do_relu) {
    int wid = (blockIdx.x * 256 + threadIdx.x) >> 6;   // one wave64 per node
    int lane = threadIdx.x & 63;
    if (wid >= n) return;
    int s = off[wid], e = off[wid + 1];
    int hA = lane >> 5;          // head 0/1 for feature lane
    int hB = hA + 2;             // head 2/3 for feature lane+64
    int cA = lane, cB = lane + 64;
    float adA = ad_in[wid * 4 + hA];
    float adB = ad_in[wid * 4 + hB];
    float accA = 0.f, accB = 0.f, denA = 0.f, denB = 0.f;
    for (int i = s; i < e; ++i) {
        int src = sorted_src[i];
        float sA = as_in[src * 4 + hA] + adA;
        float sB = as_in[src * 4 + hB] + adB;
        sA = sA > 0.f ? sA : 0.2f * sA;
        sB = sB > 0.f ? sB : 0.2f * sB;
        float wA = __expf(sA), wB = __expf(sB);
        accA += wA * H[src * 128 + cA];
        accB += wB * H[src * 128 + cB];
        denA += wA; denB += wB;
    }
    float oA = (e > s) ? accA / denA : 0.f;
    float oB = (e > s) ? accB / denB : 0.f;
    oA += bias[cA]; oB += bias[cB];
    if (do_relu) { oA = fmaxf(oA, 0.f); oB = fmaxf(oB, 0.f); }
    OUT[wid * 128 + cA] = oA;
    OUT[wid * 128 + cB] = oB;
}

// ---------------------------------------------------------------------------
extern "C" void kernel_launch(void* const* d_in, const int* in_sizes, int n_in,
                              void* d_out, int out_size, void* d_ws, size_t ws_size,
                              hipStream_t stream) {
    const float* x        = (const float*)d_in[0];
    const int*   edge     = (const int*)d_in[1];
    const float* W0       = (const float*)d_in[2];
    const float* att_src0 = (const float*)d_in[3];
    const float* att_dst0 = (const float*)d_in[4];
    const float* b0       = (const float*)d_in[5];
    const float* W1       = (const float*)d_in[6];
    const float* att_src1 = (const float*)d_in[7];
    const float* att_dst1 = (const float*)d_in[8];
    const float* b1       = (const float*)d_in[9];
    const int* src = edge;
    const int* dst = edge + N_EDGES;
    float* out = (float*)d_out;

    // workspace layout (256B aligned slices)
    char* ws = (char*)d_ws;
    size_t o = 0;
    auto alloc = [&](size_t bytes) { char* p = ws + o; o += (bytes + 255) & ~(size_t)255; return p; };
    float* h0     = (float*)alloc((size_t)N_NODES * 128 * 4);  // 25.6 MB
    float* asb    = (float*)alloc((size_t)N_NODES * 4 * 4);
    float* adb    = (float*)alloc((size_t)N_NODES * 4 * 4);
    int*   deg    = (int*)alloc((size_t)SCAN_PAD * 4);
    int*   excl   = (int*)alloc((size_t)SCAN_PAD * 4);
    int*   bsum   = (int*)alloc(64 * 4);
    int*   off    = (int*)alloc((size_t)(N_NODES + 1) * 4);
    int*   cursor = (int*)alloc((size_t)N_NODES * 4);
    int*   sorted = (int*)alloc((size_t)N_EDGES * 4);
    float* h1 = out;  // layer-0 output lives in d_out, fully overwritten at the end

    // ---- counting sort of edges by dst (shared by both layers) ----
    hipMemsetAsync(deg, 0, (size_t)SCAN_PAD * 4, stream);
    edge_hist<<<(N_EDGES + 255) / 256, 256, 0, stream>>>(dst, deg, N_EDGES);
    scan_block<<<SCAN_PAD / 1024, 1024, 0, stream>>>(deg, excl, bsum, SCAN_PAD);
    scan_bsums<<<1, 64, 0, stream>>>(bsum, SCAN_PAD / 1024);
    add_offsets<<<(N_NODES + 256) / 256, 256, 0, stream>>>(excl, bsum, off, cursor, N_NODES, N_EDGES);
    edge_scatter<<<(N_EDGES + 255) / 256, 256, 0, stream>>>(src, dst, cursor, sorted, N_EDGES);

    int agg_blocks = (N_NODES + 3) / 4;   // 4 waves per 256-thread block

    // ---- layer 0 ----
    gemm_x128<<<1536, 256, 0, stream>>>(x, W0, h0, N_NODES);
    attn_scores<<<N_NODES, 128, 0, stream>>>(h0, att_src0, att_dst0, asb, adb, N_NODES);
    gat_aggregate<<<agg_blocks, 256, 0, stream>>>(h0, off, sorted, asb, adb, b0, h1, N_NODES, 1);

    // ---- layer 1 ----
    gemm_x128<<<1536, 256, 0, stream>>>(h1, W1, h0, N_NODES);   // h0 reused as h2
    attn_scores<<<N_NODES, 128, 0, stream>>>(h0, att_src1, att_dst1, asb, adb, N_NODES);
    gat_aggregate<<<agg_blocks, 256, 0, stream>>>(h0, off, sorted, asb, adb, b1, out, N_NODES, 0);
}

// Round 2
// 455.138 us; speedup vs baseline: 1.5150x; 1.5150x over previous
//
#include <hip/hip_runtime.h>
#include <hip/hip_fp16.h>

#define N_NODES 50000
#define N_EDGES 1600000
#define SCAN_PAD 50176   // 49 * 1024

// ---- GEMM fused: H16 = half(X @ W), a_s/a_d scores from the epilogue -------
__global__ __launch_bounds__(256) void gemm_fused(const float* __restrict__ X,
                                                  const float* __restrict__ W,
                                                  const float* __restrict__ att_s,
                                                  const float* __restrict__ att_d,
                                                  __half* __restrict__ H16,
                                                  float* __restrict__ as_out,
                                                  float* __restrict__ ad_out, int nrows) {
    __shared__ float Wl[128 * 128];   // 64 KB
    __shared__ float xs[16][128];     // 8 KB
    int t = threadIdx.x;
    for (int i = t; i < 128 * 128; i += 256) Wl[i] = W[i];
    int lane32 = t & 31, rgrp = t >> 5;      // rgrp 0..7
    int c0 = lane32 * 4;
    int head = lane32 >> 3;                  // c0>>5: head owning cols c0..c0+3
    float4 As = *reinterpret_cast<const float4*>(&att_s[c0]);
    float4 Ad = *reinterpret_cast<const float4*>(&att_d[c0]);
    for (int row0 = blockIdx.x * 16; row0 < nrows; row0 += gridDim.x * 16) {
        __syncthreads();   // covers W on first pass, xs-reuse on later passes
        for (int i = t; i < 2048; i += 256) {
            int rr = row0 + (i >> 7);
            xs[i >> 7][i & 127] = (rr < nrows) ? X[rr * 128 + (i & 127)] : 0.f;
        }
        __syncthreads();
        float4 a0 = make_float4(0, 0, 0, 0), a1 = make_float4(0, 0, 0, 0);
        #pragma unroll 4
        for (int k = 0; k < 128; ++k) {
            float4 w4 = *reinterpret_cast<const float4*>(&Wl[k * 128 + c0]);
            float x0 = xs[rgrp][k], x1 = xs[rgrp + 8][k];
            a0.x += x0 * w4.x; a0.y += x0 * w4.y; a0.z += x0 * w4.z; a0.w += x0 * w4.w;
            a1.x += x1 * w4.x; a1.y += x1 * w4.y; a1.z += x1 * w4.z; a1.w += x1 * w4.w;
        }
        // per-thread partial attention dots (cols c0..c0+3, all in `head`)
        float ps0 = a0.x * As.x + a0.y * As.y + a0.z * As.z + a0.w * As.w;
        float pd0 = a0.x * Ad.x + a0.y * Ad.y + a0.z * Ad.z + a0.w * Ad.w;
        float ps1 = a1.x * As.x + a1.y * As.y + a1.z * As.z + a1.w * As.w;
        float pd1 = a1.x * Ad.x + a1.y * Ad.y + a1.z * Ad.z + a1.w * Ad.w;
        #pragma unroll
        for (int m = 4; m >= 1; m >>= 1) {
            ps0 += __shfl_xor(ps0, m); pd0 += __shfl_xor(pd0, m);
            ps1 += __shfl_xor(ps1, m); pd1 += __shfl_xor(pd1, m);
        }
        int r0 = row0 + rgrp, r1 = r0 + 8;
        if (r0 < nrows) {
            union { __half2 h2[2]; float2 f2; } u;
            u.h2[0] = __floats2half2_rn(a0.x, a0.y);
            u.h2[1] = __floats2half2_rn(a0.z, a0.w);
            *reinterpret_cast<float2*>(&H16[r0 * 128 + c0]) = u.f2;
            if ((lane32 & 7) == 0) { as_out[r0 * 4 + head] = ps0; ad_out[r0 * 4 + head] = pd0; }
        }
        if (r1 < nrows) {
            union { __half2 h2[2]; float2 f2; } u;
            u.h2[0] = __floats2half2_rn(a1.x, a1.y);
            u.h2[1] = __floats2half2_rn(a1.z, a1.w);
            *reinterpret_cast<float2*>(&H16[r1 * 128 + c0]) = u.f2;
            if ((lane32 & 7) == 0) { as_out[r1 * 4 + head] = ps1; ad_out[r1 * 4 + head] = pd1; }
        }
    }
}

// ---------------- counting sort of edges by dst ----------------------------
__global__ __launch_bounds__(256) void edge_hist(const int* __restrict__ dst,
                                                 int* __restrict__ deg, int E) {
    int e = blockIdx.x * 256 + threadIdx.x;
    if (e < E) atomicAdd(&deg[dst[e]], 1);
}

__global__ __launch_bounds__(1024) void scan_block(const int* __restrict__ deg,
                                                   int* __restrict__ excl,
                                                   int* __restrict__ bsum, int n) {
    __shared__ int sh[1024];
    int g = blockIdx.x * 1024 + threadIdx.x;
    int v = (g < n) ? deg[g] : 0;
    sh[threadIdx.x] = v;
    __syncthreads();
    for (int off = 1; off < 1024; off <<= 1) {
        int tv = (threadIdx.x >= off) ? sh[threadIdx.x - off] : 0;
        __syncthreads();
        sh[threadIdx.x] += tv;
        __syncthreads();
    }
    if (g < n) excl[g] = sh[threadIdx.x] - v;
    if (threadIdx.x == 1023) bsum[blockIdx.x] = sh[1023];
}

__global__ void scan_bsums(int* bsum, int nb) {
    if (blockIdx.x == 0 && threadIdx.x == 0) {
        int acc = 0;
        for (int i = 0; i < nb; ++i) { int v = bsum[i]; bsum[i] = acc; acc += v; }
    }
}

__global__ __launch_bounds__(256) void add_offsets(const int* __restrict__ excl,
                                                   const int* __restrict__ bsum,
                                                   int* __restrict__ off,
                                                   int* __restrict__ cursor,
                                                   int n, int E) {
    int g = blockIdx.x * 256 + threadIdx.x;
    if (g < n) {
        int v = excl[g] + bsum[g >> 10];
        off[g] = v;
        cursor[g] = v;
    }
    if (g == n) off[n] = E;
}

__global__ __launch_bounds__(256) void edge_scatter(const int* __restrict__ src,
                                                    const int* __restrict__ dst,
                                                    int* __restrict__ cursor,
                                                    int* __restrict__ sorted_src, int E) {
    int e = blockIdx.x * 256 + threadIdx.x;
    if (e < E) {
        int d = dst[e];
        int p = atomicAdd(&cursor[d], 1);
        sorted_src[p] = src[e];
    }
}

// ---- fused softmax + aggregate, fp16 gather, 4-deep MLP --------------------
__device__ __forceinline__ float leaky_exp(float v) {
    v = v > 0.f ? v : 0.2f * v;
    return __expf(v);
}

__global__ __launch_bounds__(256) void gat_aggregate16(const __half* __restrict__ H16,
                                                       const int* __restrict__ off,
                                                       const int* __restrict__ ssrc,
                                                       const float* __restrict__ as_in,
                                                       const float* __restrict__ ad_in,
                                                       const float* __restrict__ bias,
                                                       float* __restrict__ OUT,
                                                       int n, int do_relu) {
    int wid = (blockIdx.x * 256 + threadIdx.x) >> 6;   // one wave64 per node
    int lane = threadIdx.x & 63;
    if (wid >= n) return;
    int s = off[wid], e = off[wid + 1];
    int head = lane >> 4;                 // lane owns cols 2l,2l+1 -> head (2l)>>5
    int c = lane * 2;
    float adv = ad_in[wid * 4 + head];
    float accx = 0.f, accy = 0.f, den = 0.f;
    int i = s;
    for (; i + 4 <= e; i += 4) {
        int s0 = ssrc[i], s1 = ssrc[i + 1], s2 = ssrc[i + 2], s3 = ssrc[i + 3];
        float e0 = as_in[s0 * 4 + head];
        float e1 = as_in[s1 * 4 + head];
        float e2 = as_in[s2 * 4 + head];
        float e3 = as_in[s3 * 4 + head];
        __half2 b0 = *reinterpret_cast<const __half2*>(&H16[s0 * 128 + c]);
        __half2 b1 = *reinterpret_cast<const __half2*>(&H16[s1 * 128 + c]);
        __half2 b2 = *reinterpret_cast<const __half2*>(&H16[s2 * 128 + c]);
        __half2 b3 = *reinterpret_cast<const __half2*>(&H16[s3 * 128 + c]);
        float w0 = leaky_exp(e0 + adv), w1 = leaky_exp(e1 + adv);
        float w2 = leaky_exp(e2 + adv), w3 = leaky_exp(e3 + adv);
        float2 f0 = __half22float2(b0), f1 = __half22float2(b1);
        float2 f2 = __half22float2(b2), f3 = __half22float2(b3);
        accx += w0 * f0.x; accy += w0 * f0.y;
        accx += w1 * f1.x; accy += w1 * f1.y;
        accx += w2 * f2.x; accy += w2 * f2.y;
        accx += w3 * f3.x; accy += w3 * f3.y;
        den += w0 + w1 + w2 + w3;
    }
    for (; i < e; ++i) {
        int s0 = ssrc[i];
        float w0 = leaky_exp(as_in[s0 * 4 + head] + adv);
        float2 f0 = __half22float2(*reinterpret_cast<const __half2*>(&H16[s0 * 128 + c]));
        accx += w0 * f0.x; accy += w0 * f0.y; den += w0;
    }
    float ox = (e > s) ? accx / den : 0.f;
    float oy = (e > s) ? accy / den : 0.f;
    float2 bv = *reinterpret_cast<const float2*>(&bias[c]);
    ox += bv.x; oy += bv.y;
    if (do_relu) { ox = fmaxf(ox, 0.f); oy = fmaxf(oy, 0.f); }
    *reinterpret_cast<float2*>(&OUT[wid * 128 + c]) = make_float2(ox, oy);
}

// ---------------------------------------------------------------------------
extern "C" void kernel_launch(void* const* d_in, const int* in_sizes, int n_in,
                              void* d_out, int out_size, void* d_ws, size_t ws_size,
                              hipStream_t stream) {
    const float* x        = (const float*)d_in[0];
    const int*   edge     = (const int*)d_in[1];
    const float* W0       = (const float*)d_in[2];
    const float* att_src0 = (const float*)d_in[3];
    const float* att_dst0 = (const float*)d_in[4];
    const float* b0       = (const float*)d_in[5];
    const float* W1       = (const float*)d_in[6];
    const float* att_src1 = (const float*)d_in[7];
    const float* att_dst1 = (const float*)d_in[8];
    const float* b1       = (const float*)d_in[9];
    const int* src = edge;
    const int* dst = edge + N_EDGES;
    float* out = (float*)d_out;

    char* ws = (char*)d_ws;
    size_t o = 0;
    auto alloc = [&](size_t bytes) { char* p = ws + o; o += (bytes + 255) & ~(size_t)255; return p; };
    __half* H16   = (__half*)alloc((size_t)N_NODES * 128 * 2);  // 12.8 MB
    float* asb    = (float*)alloc((size_t)N_NODES * 4 * 4);
    float* adb    = (float*)alloc((size_t)N_NODES * 4 * 4);
    int*   deg    = (int*)alloc((size_t)SCAN_PAD * 4);
    int*   excl   = (int*)alloc((size_t)SCAN_PAD * 4);
    int*   bsum   = (int*)alloc(64 * 4);
    int*   off    = (int*)alloc((size_t)(N_NODES + 1) * 4);
    int*   cursor = (int*)alloc((size_t)N_NODES * 4);
    int*   sorted = (int*)alloc((size_t)N_EDGES * 4);
    float* h1 = out;  // layer-0 fp32 output lives in d_out, overwritten at the end

    // ---- counting sort of edges by dst (shared by both layers) ----
    hipMemsetAsync(deg, 0, (size_t)SCAN_PAD * 4, stream);
    edge_hist<<<(N_EDGES + 255) / 256, 256, 0, stream>>>(dst, deg, N_EDGES);
    scan_block<<<SCAN_PAD / 1024, 1024, 0, stream>>>(deg, excl, bsum, SCAN_PAD);
    scan_bsums<<<1, 64, 0, stream>>>(bsum, SCAN_PAD / 1024);
    add_offsets<<<(N_NODES + 256) / 256, 256, 0, stream>>>(excl, bsum, off, cursor, N_NODES, N_EDGES);
    edge_scatter<<<(N_EDGES + 255) / 256, 256, 0, stream>>>(src, dst, cursor, sorted, N_EDGES);

    int agg_blocks = (N_NODES + 3) / 4;   // 4 waves per 256-thread block

    // ---- layer 0 ----
    gemm_fused<<<1536, 256, 0, stream>>>(x, W0, att_src0, att_dst0, H16, asb, adb, N_NODES);
    gat_aggregate16<<<agg_blocks, 256, 0, stream>>>(H16, off, sorted, asb, adb, b0, h1, N_NODES, 1);

    // ---- layer 1 ----
    gemm_fused<<<1536, 256, 0, stream>>>(h1, W1, att_src1, att_dst1, H16, asb, adb, N_NODES);
    gat_aggregate16<<<agg_blocks, 256, 0, stream>>>(H16, off, sorted, asb, adb, b1, out, N_NODES, 0);
}

// Round 3
// 284.554 us; speedup vs baseline: 2.4232x; 1.5995x over previous
//
#include <hip/hip_runtime.h>
#include <hip/hip_fp16.h>

#define N_NODES 50000
#define N_EDGES 1600000
#define NB 196                  // buckets: dst>>8, 50175>>8 = 195
#define NBLK 256                // phase-A blocks
#define CHUNK (N_EDGES / NBLK)  // 6250 exactly
#define SCAN_N (NB * NBLK)      // 50176 = 49*1024 exactly

// ---- GEMM fused: H16 = half(X @ W), a_s/a_d scores from the epilogue -------
__global__ __launch_bounds__(256) void gemm_fused(const float* __restrict__ X,
                                                  const float* __restrict__ W,
                                                  const float* __restrict__ att_s,
                                                  const float* __restrict__ att_d,
                                                  __half* __restrict__ H16,
                                                  float* __restrict__ as_out,
                                                  float* __restrict__ ad_out, int nrows) {
    __shared__ float Wl[128 * 128];   // 64 KB
    __shared__ float xs[16][128];     // 8 KB
    int t = threadIdx.x;
    for (int i = t; i < 128 * 128; i += 256) Wl[i] = W[i];
    int lane32 = t & 31, rgrp = t >> 5;      // rgrp 0..7
    int c0 = lane32 * 4;
    int head = lane32 >> 3;                  // c0>>5: head owning cols c0..c0+3
    float4 As = *reinterpret_cast<const float4*>(&att_s[c0]);
    float4 Ad = *reinterpret_cast<const float4*>(&att_d[c0]);
    for (int row0 = blockIdx.x * 16; row0 < nrows; row0 += gridDim.x * 16) {
        __syncthreads();   // covers W on first pass, xs-reuse on later passes
        for (int i = t; i < 2048; i += 256) {
            int rr = row0 + (i >> 7);
            xs[i >> 7][i & 127] = (rr < nrows) ? X[rr * 128 + (i & 127)] : 0.f;
        }
        __syncthreads();
        float4 a0 = make_float4(0, 0, 0, 0), a1 = make_float4(0, 0, 0, 0);
        #pragma unroll 4
        for (int k = 0; k < 128; ++k) {
            float4 w4 = *reinterpret_cast<const float4*>(&Wl[k * 128 + c0]);
            float x0 = xs[rgrp][k], x1 = xs[rgrp + 8][k];
            a0.x += x0 * w4.x; a0.y += x0 * w4.y; a0.z += x0 * w4.z; a0.w += x0 * w4.w;
            a1.x += x1 * w4.x; a1.y += x1 * w4.y; a1.z += x1 * w4.z; a1.w += x1 * w4.w;
        }
        float ps0 = a0.x * As.x + a0.y * As.y + a0.z * As.z + a0.w * As.w;
        float pd0 = a0.x * Ad.x + a0.y * Ad.y + a0.z * Ad.z + a0.w * Ad.w;
        float ps1 = a1.x * As.x + a1.y * As.y + a1.z * As.z + a1.w * As.w;
        float pd1 = a1.x * Ad.x + a1.y * Ad.y + a1.z * Ad.z + a1.w * Ad.w;
        #pragma unroll
        for (int m = 4; m >= 1; m >>= 1) {
            ps0 += __shfl_xor(ps0, m); pd0 += __shfl_xor(pd0, m);
            ps1 += __shfl_xor(ps1, m); pd1 += __shfl_xor(pd1, m);
        }
        int r0 = row0 + rgrp, r1 = r0 + 8;
        if (r0 < nrows) {
            union { __half2 h2[2]; float2 f2; } u;
            u.h2[0] = __floats2half2_rn(a0.x, a0.y);
            u.h2[1] = __floats2half2_rn(a0.z, a0.w);
            *reinterpret_cast<float2*>(&H16[r0 * 128 + c0]) = u.f2;
            if ((lane32 & 7) == 0) { as_out[r0 * 4 + head] = ps0; ad_out[r0 * 4 + head] = pd0; }
        }
        if (r1 < nrows) {
            union { __half2 h2[2]; float2 f2; } u;
            u.h2[0] = __floats2half2_rn(a1.x, a1.y);
            u.h2[1] = __floats2half2_rn(a1.z, a1.w);
            *reinterpret_cast<float2*>(&H16[r1 * 128 + c0]) = u.f2;
            if ((lane32 & 7) == 0) { as_out[r1 * 4 + head] = ps1; ad_out[r1 * 4 + head] = pd1; }
        }
    }
}

// ---------------- bucketed two-phase sort of edges by dst ------------------
// Phase A1: per-block bucket histogram (bucket-major layout for the scan)
__global__ __launch_bounds__(1024) void bucket_hist(const int* __restrict__ dst,
                                                    int* __restrict__ counts) {
    __shared__ int hist[NB];
    int t = threadIdx.x, b = blockIdx.x;
    if (t < NB) hist[t] = 0;
    __syncthreads();
    int s = b * CHUNK;
    for (int i = t; i < CHUNK; i += 1024)
        atomicAdd(&hist[dst[s + i] >> 8], 1);
    __syncthreads();
    if (t < NB) counts[t * NBLK + b] = hist[t];
}

__global__ __launch_bounds__(1024) void scan_block(const int* __restrict__ v_in,
                                                   int* __restrict__ excl,
                                                   int* __restrict__ bsum, int n) {
    __shared__ int sh[1024];
    int g = blockIdx.x * 1024 + threadIdx.x;
    int v = (g < n) ? v_in[g] : 0;
    sh[threadIdx.x] = v;
    __syncthreads();
    for (int off = 1; off < 1024; off <<= 1) {
        int tv = (threadIdx.x >= off) ? sh[threadIdx.x - off] : 0;
        __syncthreads();
        sh[threadIdx.x] += tv;
        __syncthreads();
    }
    if (g < n) excl[g] = sh[threadIdx.x] - v;
    if (threadIdx.x == 1023) bsum[blockIdx.x] = sh[1023];
}

__global__ void scan_bsums(int* bsum, int nb) {
    if (blockIdx.x == 0 && threadIdx.x == 0) {
        int acc = 0;
        for (int i = 0; i < nb; ++i) { int v = bsum[i]; bsum[i] = acc; acc += v; }
    }
}

__global__ __launch_bounds__(256) void finalize_scan(const int* __restrict__ excl,
                                                     const int* __restrict__ bsum,
                                                     int* __restrict__ start, int n) {
    int g = blockIdx.x * 256 + threadIdx.x;
    if (g < n) start[g] = excl[g] + bsum[g >> 10];
}

// Phase A2: scatter (src,dst) into bucket regions via LDS cursors
__global__ __launch_bounds__(1024) void bucket_scatter(const int* __restrict__ src,
                                                       const int* __restrict__ dst,
                                                       const int* __restrict__ start,
                                                       int2* __restrict__ bucketed) {
    __shared__ int cur[NB];
    int t = threadIdx.x, b = blockIdx.x;
    if (t < NB) cur[t] = start[t * NBLK + b];
    __syncthreads();
    int s = b * CHUNK;
    for (int i = t; i < CHUNK; i += 1024) {
        int d = dst[s + i];
        int p = atomicAdd(&cur[d >> 8], 1);
        bucketed[p] = make_int2(src[s + i], d);
    }
}

// Phase B: within-bucket counting sort by dst (256 nodes/bucket); emits off[]
__global__ __launch_bounds__(1024) void bucket_sort(const int2* __restrict__ bucketed,
                                                    const int* __restrict__ start,
                                                    int* __restrict__ sorted_src,
                                                    int* __restrict__ off) {
    __shared__ int cnt[256], scn[256], cur[256];
    int t = threadIdx.x, k = blockIdx.x;
    int base = start[k * NBLK];
    int end = (k + 1 < NB) ? start[(k + 1) * NBLK] : N_EDGES;
    int m = end - base;
    if (t < 256) cnt[t] = 0;
    __syncthreads();
    for (int i = t; i < m; i += 1024)
        atomicAdd(&cnt[bucketed[base + i].y & 255], 1);
    __syncthreads();
    if (t < 256) scn[t] = cnt[t];
    __syncthreads();
    for (int o = 1; o < 256; o <<= 1) {
        int v = (t < 256 && t >= o) ? scn[t - o] : 0;
        __syncthreads();
        if (t < 256) scn[t] += v;
        __syncthreads();
    }
    if (t < 256) {
        int excl = scn[t] - cnt[t];        // exclusive within bucket
        cur[t] = base + excl;
        int node = k * 256 + t;
        if (node <= N_NODES) off[node] = base + excl;   // node==N gets E
    }
    __syncthreads();
    for (int i = t; i < m; i += 1024) {
        int2 rec = bucketed[base + i];
        int p = atomicAdd(&cur[rec.y & 255], 1);
        sorted_src[p] = rec.x;
    }
}

// ---- fused softmax + aggregate, fp16 gather, 4-deep MLP --------------------
__device__ __forceinline__ float leaky_exp(float v) {
    v = v > 0.f ? v : 0.2f * v;
    return __expf(v);
}

__global__ __launch_bounds__(256) void gat_aggregate16(const __half* __restrict__ H16,
                                                       const int* __restrict__ off,
                                                       const int* __restrict__ ssrc,
                                                       const float* __restrict__ as_in,
                                                       const float* __restrict__ ad_in,
                                                       const float* __restrict__ bias,
                                                       float* __restrict__ OUT,
                                                       int n, int do_relu) {
    int wid = (blockIdx.x * 256 + threadIdx.x) >> 6;   // one wave64 per node
    int lane = threadIdx.x & 63;
    if (wid >= n) return;
    int s = off[wid], e = off[wid + 1];
    int head = lane >> 4;                 // lane owns cols 2l,2l+1 -> head (2l)>>5
    int c = lane * 2;
    float adv = ad_in[wid * 4 + head];
    float accx = 0.f, accy = 0.f, den = 0.f;
    int i = s;
    for (; i + 4 <= e; i += 4) {
        int s0 = ssrc[i], s1 = ssrc[i + 1], s2 = ssrc[i + 2], s3 = ssrc[i + 3];
        float e0 = as_in[s0 * 4 + head];
        float e1 = as_in[s1 * 4 + head];
        float e2 = as_in[s2 * 4 + head];
        float e3 = as_in[s3 * 4 + head];
        __half2 b0 = *reinterpret_cast<const __half2*>(&H16[s0 * 128 + c]);
        __half2 b1 = *reinterpret_cast<const __half2*>(&H16[s1 * 128 + c]);
        __half2 b2 = *reinterpret_cast<const __half2*>(&H16[s2 * 128 + c]);
        __half2 b3 = *reinterpret_cast<const __half2*>(&H16[s3 * 128 + c]);
        float w0 = leaky_exp(e0 + adv), w1 = leaky_exp(e1 + adv);
        float w2 = leaky_exp(e2 + adv), w3 = leaky_exp(e3 + adv);
        float2 f0 = __half22float2(b0), f1 = __half22float2(b1);
        float2 f2 = __half22float2(b2), f3 = __half22float2(b3);
        accx += w0 * f0.x; accy += w0 * f0.y;
        accx += w1 * f1.x; accy += w1 * f1.y;
        accx += w2 * f2.x; accy += w2 * f2.y;
        accx += w3 * f3.x; accy += w3 * f3.y;
        den += w0 + w1 + w2 + w3;
    }
    for (; i < e; ++i) {
        int s0 = ssrc[i];
        float w0 = leaky_exp(as_in[s0 * 4 + head] + adv);
        float2 f0 = __half22float2(*reinterpret_cast<const __half2*>(&H16[s0 * 128 + c]));
        accx += w0 * f0.x; accy += w0 * f0.y; den += w0;
    }
    float ox = (e > s) ? accx / den : 0.f;
    float oy = (e > s) ? accy / den : 0.f;
    float2 bv = *reinterpret_cast<const float2*>(&bias[c]);
    ox += bv.x; oy += bv.y;
    if (do_relu) { ox = fmaxf(ox, 0.f); oy = fmaxf(oy, 0.f); }
    *reinterpret_cast<float2*>(&OUT[wid * 128 + c]) = make_float2(ox, oy);
}

// ---------------------------------------------------------------------------
extern "C" void kernel_launch(void* const* d_in, const int* in_sizes, int n_in,
                              void* d_out, int out_size, void* d_ws, size_t ws_size,
                              hipStream_t stream) {
    const float* x        = (const float*)d_in[0];
    const int*   edge     = (const int*)d_in[1];
    const float* W0       = (const float*)d_in[2];
    const float* att_src0 = (const float*)d_in[3];
    const float* att_dst0 = (const float*)d_in[4];
    const float* b0       = (const float*)d_in[5];
    const float* W1       = (const float*)d_in[6];
    const float* att_src1 = (const float*)d_in[7];
    const float* att_dst1 = (const float*)d_in[8];
    const float* b1       = (const float*)d_in[9];
    const int* src = edge;
    const int* dst = edge + N_EDGES;
    float* out = (float*)d_out;

    char* ws = (char*)d_ws;
    size_t o = 0;
    auto alloc = [&](size_t bytes) { char* p = ws + o; o += (bytes + 255) & ~(size_t)255; return p; };
    __half* H16    = (__half*)alloc((size_t)N_NODES * 128 * 2);   // 12.8 MB
    float* asb     = (float*)alloc((size_t)N_NODES * 4 * 4);
    float* adb     = (float*)alloc((size_t)N_NODES * 4 * 4);
    int*   counts  = (int*)alloc((size_t)SCAN_N * 4);
    int*   excl    = (int*)alloc((size_t)SCAN_N * 4);
    int*   bsum    = (int*)alloc(64 * 4);
    int*   start   = (int*)alloc((size_t)SCAN_N * 4);
    int*   off     = (int*)alloc((size_t)(N_NODES + 1) * 4);
    int2*  bucketed = (int2*)alloc((size_t)N_EDGES * 8);          // 12.8 MB
    int*   sorted  = (int*)alloc((size_t)N_EDGES * 4);            // 6.4 MB
    float* h1 = out;  // layer-0 fp32 output lives in d_out, overwritten at the end

    // ---- bucketed counting sort of edges by dst (shared by both layers) ----
    bucket_hist<<<NBLK, 1024, 0, stream>>>(dst, counts);
    scan_block<<<SCAN_N / 1024, 1024, 0, stream>>>(counts, excl, bsum, SCAN_N);
    scan_bsums<<<1, 64, 0, stream>>>(bsum, SCAN_N / 1024);
    finalize_scan<<<(SCAN_N + 255) / 256, 256, 0, stream>>>(excl, bsum, start, SCAN_N);
    bucket_scatter<<<NBLK, 1024, 0, stream>>>(src, dst, start, bucketed);
    bucket_sort<<<NB, 1024, 0, stream>>>(bucketed, start, sorted, off);

    int agg_blocks = (N_NODES + 3) / 4;   // 4 waves per 256-thread block

    // ---- layer 0 ----
    gemm_fused<<<1536, 256, 0, stream>>>(x, W0, att_src0, att_dst0, H16, asb, adb, N_NODES);
    gat_aggregate16<<<agg_blocks, 256, 0, stream>>>(H16, off, sorted, asb, adb, b0, h1, N_NODES, 1);

    // ---- layer 1 ----
    gemm_fused<<<1536, 256, 0, stream>>>(h1, W1, att_src1, att_dst1, H16, asb, adb, N_NODES);
    gat_aggregate16<<<agg_blocks, 256, 0, stream>>>(H16, off, sorted, asb, adb, b1, out, N_NODES, 0);
}

// Round 4
// 230.164 us; speedup vs baseline: 2.9958x; 1.2363x over previous
//
#include <hip/hip_runtime.h>
#include <hip/hip_fp16.h>

#define N_NODES 50000
#define N_EDGES 1600000
#define NB 196                  // buckets: dst>>8
#define NBLK 256                // phase-A blocks
#define CHUNK (N_EDGES / NBLK)  // 6250
#define SCAN_N (NB * NBLK)      // 50176 = 49*1024

typedef _Float16 half8_t __attribute__((ext_vector_type(8)));
typedef float floatx4 __attribute__((ext_vector_type(4)));

// ---- MFMA f16 GEMM + fused attention-score epilogue -----------------------
// H16 = half(X @ W) [nrows,128]; as/ad[n,h] = per-head dots with att vectors.
__global__ __launch_bounds__(256) void gemm_mfma(const float* __restrict__ X,
                                                 const float* __restrict__ W,
                                                 const float* __restrict__ att_s,
                                                 const float* __restrict__ att_d,
                                                 __half* __restrict__ H16,
                                                 float* __restrict__ as_out,
                                                 float* __restrict__ ad_out, int nrows) {
    __shared__ __align__(16) char lds[49152];   // A:[0,16K) Wt:[16K,48K)
    char* Alds = lds;
    char* Wlds = lds + 16384;
    int t = threadIdx.x;
    int lane = t & 63, wv_ = t >> 6;
    // stage Wt[n][k] (f16, transposed, XOR-swizzled), once per block
    for (int p = 0; p < 16; ++p) {
        int flat = p * 256 + t;               // 4096 float4s of W[k][n]
        int k = flat >> 5;
        int n0 = (flat & 31) * 4;
        float4 wv = reinterpret_cast<const float4*>(W)[flat];
        const float* wf = reinterpret_cast<const float*>(&wv);
        #pragma unroll
        for (int i = 0; i < 4; ++i) {
            int n = n0 + i;
            int byte = (n * 256 + k * 2) ^ ((n & 7) << 4);
            *reinterpret_cast<__half*>(Wlds + byte) = __float2half(wf[i]);
        }
    }
    int col16 = lane & 15;
    float Asv[8], Adv[8];
    #pragma unroll
    for (int nt = 0; nt < 8; ++nt) {
        Asv[nt] = att_s[nt * 16 + col16];
        Adv[nt] = att_d[nt * 16 + col16];
    }
    int row0 = blockIdx.x * 64;
    // stage A rows (f16, swizzled)
    for (int p = 0; p < 8; ++p) {
        int r = p * 8 + (t >> 5);
        int f4 = t & 31;
        int rr = row0 + r;
        float4 xv = make_float4(0, 0, 0, 0);
        if (rr < nrows) xv = reinterpret_cast<const float4*>(X)[(size_t)rr * 32 + f4];
        uint2 hv;
        __half2* hp = reinterpret_cast<__half2*>(&hv);
        hp[0] = __floats2half2_rn(xv.x, xv.y);
        hp[1] = __floats2half2_rn(xv.z, xv.w);
        int byte = (r * 256 + f4 * 8) ^ ((r & 7) << 4);
        *reinterpret_cast<uint2*>(Alds + byte) = hv;
    }
    __syncthreads();
    // fragments: A row = wv_*16 + (lane&15); k = kb*32 + (lane>>4)*8 + j
    int ksub = (lane >> 4) * 16;              // byte offset of k-slice
    int rloc = wv_ * 16 + col16;
    half8_t afr[4];
    #pragma unroll
    for (int kb = 0; kb < 4; ++kb) {
        int byte = (rloc * 256 + kb * 64 + ksub) ^ ((rloc & 7) << 4);
        afr[kb] = *reinterpret_cast<half8_t*>(Alds + byte);
    }
    floatx4 acc[8];
    #pragma unroll
    for (int nt = 0; nt < 8; ++nt) {
        int n = nt * 16 + col16;
        floatx4 a = {0.f, 0.f, 0.f, 0.f};
        #pragma unroll
        for (int kb = 0; kb < 4; ++kb) {
            int byte = (n * 256 + kb * 64 + ksub) ^ ((n & 7) << 4);
            half8_t bfr = *reinterpret_cast<half8_t*>(Wlds + byte);
            a = __builtin_amdgcn_mfma_f32_16x16x32_f16(afr[kb], bfr, a, 0, 0, 0);
        }
        acc[nt] = a;
    }
    // epilogue: D row=(lane>>4)*4+reg, col=nt*16+(lane&15)
    float ps[4][4], pd[4][4];   // [reg][head]
    #pragma unroll
    for (int reg = 0; reg < 4; ++reg)
        #pragma unroll
        for (int h = 0; h < 4; ++h) {
            ps[reg][h] = acc[2*h][reg] * Asv[2*h] + acc[2*h+1][reg] * Asv[2*h+1];
            pd[reg][h] = acc[2*h][reg] * Adv[2*h] + acc[2*h+1][reg] * Adv[2*h+1];
        }
    #pragma unroll
    for (int m = 1; m <= 8; m <<= 1)
        #pragma unroll
        for (int reg = 0; reg < 4; ++reg)
            #pragma unroll
            for (int h = 0; h < 4; ++h) {
                ps[reg][h] += __shfl_xor(ps[reg][h], m);
                pd[reg][h] += __shfl_xor(pd[reg][h], m);
            }
    int rbase = row0 + wv_ * 16 + (lane >> 4) * 4;
    #pragma unroll
    for (int reg = 0; reg < 4; ++reg) {
        int grow = rbase + reg;
        if (grow < nrows) {
            #pragma unroll
            for (int nt = 0; nt < 8; ++nt)
                H16[(size_t)grow * 128 + nt * 16 + col16] = __float2half(acc[nt][reg]);
            if (col16 == 0) {
                *reinterpret_cast<float4*>(as_out + (size_t)grow * 4) =
                    make_float4(ps[reg][0], ps[reg][1], ps[reg][2], ps[reg][3]);
                *reinterpret_cast<float4*>(ad_out + (size_t)grow * 4) =
                    make_float4(pd[reg][0], pd[reg][1], pd[reg][2], pd[reg][3]);
            }
        }
    }
}

// ---------------- bucketed two-phase sort (packed records) -----------------
__global__ __launch_bounds__(1024) void bucket_hist(const int* __restrict__ dst,
                                                    int* __restrict__ counts) {
    __shared__ int hist[NB];
    int t = threadIdx.x, b = blockIdx.x;
    if (t < NB) hist[t] = 0;
    __syncthreads();
    int s = b * CHUNK;
    for (int i = t; i < CHUNK; i += 1024)
        atomicAdd(&hist[dst[s + i] >> 8], 1);
    __syncthreads();
    if (t < NB) counts[t * NBLK + b] = hist[t];
}

__global__ __launch_bounds__(1024) void scan_block(const int* __restrict__ v_in,
                                                   int* __restrict__ excl,
                                                   int* __restrict__ bsum, int n) {
    __shared__ int sh[1024];
    int g = blockIdx.x * 1024 + threadIdx.x;
    int v = (g < n) ? v_in[g] : 0;
    sh[threadIdx.x] = v;
    __syncthreads();
    for (int off = 1; off < 1024; off <<= 1) {
        int tv = (threadIdx.x >= off) ? sh[threadIdx.x - off] : 0;
        __syncthreads();
        sh[threadIdx.x] += tv;
        __syncthreads();
    }
    if (g < n) excl[g] = sh[threadIdx.x] - v;
    if (threadIdx.x == 1023) bsum[blockIdx.x] = sh[1023];
}

__global__ void scan_bsums(int* bsum, int nb) {
    if (blockIdx.x == 0 && threadIdx.x == 0) {
        int acc = 0;
        for (int i = 0; i < nb; ++i) { int v = bsum[i]; bsum[i] = acc; acc += v; }
    }
}

__global__ __launch_bounds__(256) void finalize_scan(const int* __restrict__ excl,
                                                     const int* __restrict__ bsum,
                                                     int* __restrict__ start, int n) {
    int g = blockIdx.x * 256 + threadIdx.x;
    if (g < n) start[g] = excl[g] + bsum[g >> 10];
}

__global__ __launch_bounds__(1024) void bucket_scatter(const int* __restrict__ src,
                                                       const int* __restrict__ dst,
                                                       const int* __restrict__ start,
                                                       int* __restrict__ bucketed) {
    __shared__ int cur[NB];
    int t = threadIdx.x, b = blockIdx.x;
    if (t < NB) cur[t] = start[t * NBLK + b];
    __syncthreads();
    int s = b * CHUNK;
    for (int i = t; i < CHUNK; i += 1024) {
        int d = dst[s + i];
        int p = atomicAdd(&cur[d >> 8], 1);
        bucketed[p] = (src[s + i] << 8) | (d & 255);   // src < 65536
    }
}

__global__ __launch_bounds__(1024) void bucket_sort(const int* __restrict__ bucketed,
                                                    const int* __restrict__ start,
                                                    int* __restrict__ sorted_packed,
                                                    int* __restrict__ off) {
    __shared__ int cnt[256], scn[256], cur[256];
    int t = threadIdx.x, k = blockIdx.x;
    int base = start[k * NBLK];
    int end = (k + 1 < NB) ? start[(k + 1) * NBLK] : N_EDGES;
    int m = end - base;
    if (t < 256) cnt[t] = 0;
    __syncthreads();
    for (int i = t; i < m; i += 1024)
        atomicAdd(&cnt[bucketed[base + i] & 255], 1);
    __syncthreads();
    if (t < 256) scn[t] = cnt[t];
    __syncthreads();
    for (int o = 1; o < 256; o <<= 1) {
        int v = (t < 256 && t >= o) ? scn[t - o] : 0;
        __syncthreads();
        if (t < 256) scn[t] += v;
        __syncthreads();
    }
    if (t < 256) {
        int excl = scn[t] - cnt[t];
        cur[t] = base + excl;
        int node = k * 256 + t;
        if (node <= N_NODES) off[node] = base + excl;
    }
    __syncthreads();
    for (int i = t; i < m; i += 1024) {
        int rec = bucketed[base + i];
        int p = atomicAdd(&cur[rec & 255], 1);
        sorted_packed[p] = rec;
    }
}

// ---- per-edge softmax weights (no lane redundancy), fp16 ------------------
__global__ __launch_bounds__(256) void edge_weights(const int* __restrict__ packed,
                                                    const int* __restrict__ off,
                                                    const float* __restrict__ asb,
                                                    const float* __restrict__ adb,
                                                    __half* __restrict__ wgt) {
    int k = blockIdx.x;
    int base = off[k << 8];
    int endn = (k + 1) << 8; if (endn > N_NODES) endn = N_NODES;
    int end = off[endn];
    for (int i = base + blockIdx.y * 256 + threadIdx.x; i < end; i += 1024) {
        int rec = packed[i];
        int s = rec >> 8;
        int d = (k << 8) | (rec & 255);
        float4 a4 = *reinterpret_cast<const float4*>(asb + (size_t)s * 4);
        float4 d4 = *reinterpret_cast<const float4*>(adb + (size_t)d * 4);
        float w0, w1, w2, w3;
        { float v = a4.x + d4.x; v = fmaxf(v, 0.2f * v); w0 = __expf(v); }
        { float v = a4.y + d4.y; v = fmaxf(v, 0.2f * v); w1 = __expf(v); }
        { float v = a4.z + d4.z; v = fmaxf(v, 0.2f * v); w2 = __expf(v); }
        { float v = a4.w + d4.w; v = fmaxf(v, 0.2f * v); w3 = __expf(v); }
        uint2 u;
        __half2* up = reinterpret_cast<__half2*>(&u);
        up[0] = __floats2half2_rn(w0, w1);
        up[1] = __floats2half2_rn(w2, w3);
        *reinterpret_cast<uint2*>(wgt + (size_t)i * 4) = u;
    }
}

// ---- quarter-wave aggregate: 1 wave/node, 16 lanes/edge, 8 cols/lane ------
__global__ __launch_bounds__(256) void gat_aggregate_q(const __half* __restrict__ H16,
                                                       const int* __restrict__ off,
                                                       const int* __restrict__ packed,
                                                       const __half* __restrict__ wgt,
                                                       const float* __restrict__ bias,
                                                       float* __restrict__ OUT,
                                                       int n, int do_relu) {
    int wid = (blockIdx.x * 256 + threadIdx.x) >> 6;
    int lane = threadIdx.x & 63;
    if (wid >= n) return;
    int s = off[wid], e = off[wid + 1];
    int q = lane >> 4;            // which edge of the 4-group
    int sub = lane & 15;          // 16B chunk of the row (8 cols)
    int head = sub >> 2;
    int sub16 = sub * 16;
    const char* Hc = reinterpret_cast<const char*>(H16);
    float acc[8] = {0, 0, 0, 0, 0, 0, 0, 0};
    float den = 0.f;
    for (int i = s; i < e; i += 8) {
        int ia = i + q, ib = i + 4 + q;
        bool va = ia < e, vb = ib < e;
        int ja = va ? ia : s, jb = vb ? ib : s;
        int ra = packed[ja], rb = packed[jb];
        float wa = __half2float(wgt[(size_t)ja * 4 + head]);
        float wb = __half2float(wgt[(size_t)jb * 4 + head]);
        if (!va) wa = 0.f;
        if (!vb) wb = 0.f;
        uint4 ha = *reinterpret_cast<const uint4*>(Hc + (ra & 0xFFFFFF00) + sub16);
        uint4 hb = *reinterpret_cast<const uint4*>(Hc + (rb & 0xFFFFFF00) + sub16);
        const __half2* pa = reinterpret_cast<const __half2*>(&ha);
        const __half2* pb = reinterpret_cast<const __half2*>(&hb);
        #pragma unroll
        for (int j = 0; j < 4; ++j) {
            float2 fa = __half22float2(pa[j]);
            float2 fb = __half22float2(pb[j]);
            acc[2*j]   += wa * fa.x + wb * fb.x;
            acc[2*j+1] += wa * fa.y + wb * fb.y;
        }
        den += wa + wb;
    }
    #pragma unroll
    for (int j = 0; j < 8; ++j) acc[j] += __shfl_xor(acc[j], 16);
    den += __shfl_xor(den, 16);
    #pragma unroll
    for (int j = 0; j < 8; ++j) acc[j] += __shfl_xor(acc[j], 32);
    den += __shfl_xor(den, 32);
    if (q == 0) {
        float inv = den > 0.f ? 1.f / den : 0.f;
        float4 b0 = *reinterpret_cast<const float4*>(bias + sub * 8);
        float4 b1 = *reinterpret_cast<const float4*>(bias + sub * 8 + 4);
        float4 o0 = make_float4(acc[0]*inv + b0.x, acc[1]*inv + b0.y,
                                acc[2]*inv + b0.z, acc[3]*inv + b0.w);
        float4 o1 = make_float4(acc[4]*inv + b1.x, acc[5]*inv + b1.y,
                                acc[6]*inv + b1.z, acc[7]*inv + b1.w);
        if (do_relu) {
            o0 = make_float4(fmaxf(o0.x,0.f), fmaxf(o0.y,0.f), fmaxf(o0.z,0.f), fmaxf(o0.w,0.f));
            o1 = make_float4(fmaxf(o1.x,0.f), fmaxf(o1.y,0.f), fmaxf(o1.z,0.f), fmaxf(o1.w,0.f));
        }
        *reinterpret_cast<float4*>(OUT + (size_t)wid * 128 + sub * 8) = o0;
        *reinterpret_cast<float4*>(OUT + (size_t)wid * 128 + sub * 8 + 4) = o1;
    }
}

// ---------------------------------------------------------------------------
extern "C" void kernel_launch(void* const* d_in, const int* in_sizes, int n_in,
                              void* d_out, int out_size, void* d_ws, size_t ws_size,
                              hipStream_t stream) {
    const float* x        = (const float*)d_in[0];
    const int*   edge     = (const int*)d_in[1];
    const float* W0       = (const float*)d_in[2];
    const float* att_src0 = (const float*)d_in[3];
    const float* att_dst0 = (const float*)d_in[4];
    const float* b0       = (const float*)d_in[5];
    const float* W1       = (const float*)d_in[6];
    const float* att_src1 = (const float*)d_in[7];
    const float* att_dst1 = (const float*)d_in[8];
    const float* b1       = (const float*)d_in[9];
    const int* src = edge;
    const int* dst = edge + N_EDGES;
    float* out = (float*)d_out;

    char* ws = (char*)d_ws;
    size_t o = 0;
    auto alloc = [&](size_t bytes) { char* p = ws + o; o += (bytes + 255) & ~(size_t)255; return p; };
    __half* H16   = (__half*)alloc((size_t)N_NODES * 128 * 2);    // 12.8 MB (persistent)
    float* asb    = (float*)alloc((size_t)N_NODES * 4 * 4);
    float* adb    = (float*)alloc((size_t)N_NODES * 4 * 4);
    int*   off    = (int*)alloc((size_t)(N_NODES + 1) * 4);
    int*   sorted = (int*)alloc((size_t)N_EDGES * 4);             // 6.4 MB (persistent)
    // overlay region: sort temps, later reused as the per-layer weight buffer
    size_t mark = o;
    int*   counts = (int*)alloc((size_t)SCAN_N * 4);
    int*   excl   = (int*)alloc((size_t)SCAN_N * 4);
    int*   bsum   = (int*)alloc(64 * 4);
    int*   start  = (int*)alloc((size_t)SCAN_N * 4);
    int*   bucketed = (int*)alloc((size_t)N_EDGES * 4);           // 6.4 MB
    __half* wgt  = (__half*)(ws + mark);                          // 12.8 MB, aliases temps
    float* h1 = out;   // layer-0 fp32 output in d_out, overwritten at the end

    // ---- sort edges by dst (packed records; shared by both layers) ----
    bucket_hist<<<NBLK, 1024, 0, stream>>>(dst, counts);
    scan_block<<<SCAN_N / 1024, 1024, 0, stream>>>(counts, excl, bsum, SCAN_N);
    scan_bsums<<<1, 64, 0, stream>>>(bsum, SCAN_N / 1024);
    finalize_scan<<<(SCAN_N + 255) / 256, 256, 0, stream>>>(excl, bsum, start, SCAN_N);
    bucket_scatter<<<NBLK, 1024, 0, stream>>>(src, dst, start, bucketed);
    bucket_sort<<<NB, 1024, 0, stream>>>(bucketed, start, sorted, off);

    int gemm_blocks = (N_NODES + 63) / 64;
    int agg_blocks = (N_NODES + 3) / 4;
    dim3 wgrid(NB, 4);

    // ---- layer 0 ----
    gemm_mfma<<<gemm_blocks, 256, 0, stream>>>(x, W0, att_src0, att_dst0, H16, asb, adb, N_NODES);
    edge_weights<<<wgrid, 256, 0, stream>>>(sorted, off, asb, adb, wgt);
    gat_aggregate_q<<<agg_blocks, 256, 0, stream>>>(H16, off, sorted, wgt, b0, h1, N_NODES, 1);

    // ---- layer 1 ----
    gemm_mfma<<<gemm_blocks, 256, 0, stream>>>(h1, W1, att_src1, att_dst1, H16, asb, adb, N_NODES);
    edge_weights<<<wgrid, 256, 0, stream>>>(sorted, off, asb, adb, wgt);
    gat_aggregate_q<<<agg_blocks, 256, 0, stream>>>(H16, off, sorted, wgt, b1, out, N_NODES, 0);
}

// Round 5
// 222.448 us; speedup vs baseline: 3.0997x; 1.0347x over previous
//
#include <hip/hip_runtime.h>
#include <hip/hip_fp16.h>

#define N_NODES 50000
#define N_EDGES 1600000
#define NB 196                  // buckets: dst>>8
#define NBLK 256                // phase-A blocks
#define CHUNK (N_EDGES / NBLK)  // 6250
#define SCAN_N (NB * NBLK)      // 50176 = 1024*49

typedef _Float16 half8_t __attribute__((ext_vector_type(8)));
typedef float floatx4 __attribute__((ext_vector_type(4)));

// ---- MFMA f16 GEMM (persistent) + fused attention-score epilogue ----------
// H16 = half(X @ W); as/ad[n,h] = per-head dots. Input fp32 or fp16 via flag.
__global__ __launch_bounds__(256) void gemm_mfma(const float* __restrict__ Xf,
                                                 const __half* __restrict__ Xh,
                                                 int in_half,
                                                 const float* __restrict__ W,
                                                 const float* __restrict__ att_s,
                                                 const float* __restrict__ att_d,
                                                 __half* __restrict__ H16,
                                                 float* __restrict__ as_out,
                                                 float* __restrict__ ad_out, int nrows) {
    __shared__ __align__(16) char lds[49152];   // A:[0,16K) Wt:[16K,48K)
    char* Alds = lds;
    char* Wlds = lds + 16384;
    int t = threadIdx.x;
    int lane = t & 63, wv_ = t >> 6;
    // stage Wt[n][k] (f16, transposed, XOR-swizzled) ONCE per block
    for (int p = 0; p < 16; ++p) {
        int flat = p * 256 + t;               // 4096 float4s of W[k][n]
        int k = flat >> 5;
        int n0 = (flat & 31) * 4;
        float4 wv = reinterpret_cast<const float4*>(W)[flat];
        const float* wf = reinterpret_cast<const float*>(&wv);
        #pragma unroll
        for (int i = 0; i < 4; ++i) {
            int n = n0 + i;
            int byte = (n * 256 + k * 2) ^ ((n & 7) << 4);
            *reinterpret_cast<__half*>(Wlds + byte) = __float2half(wf[i]);
        }
    }
    int col16 = lane & 15;
    float Asv[8], Adv[8];
    #pragma unroll
    for (int nt = 0; nt < 8; ++nt) {
        Asv[nt] = att_s[nt * 16 + col16];
        Adv[nt] = att_d[nt * 16 + col16];
    }
    int ksub = (lane >> 4) * 16;              // byte offset of k-slice
    int rloc = wv_ * 16 + col16;
    int ntiles = (nrows + 63) / 64;
    for (int tile = blockIdx.x; tile < ntiles; tile += gridDim.x) {
        int row0 = tile * 64;
        __syncthreads();   // Alds reuse guard (and W visibility on iter 0)
        for (int p = 0; p < 8; ++p) {
            int r = p * 8 + (t >> 5);
            int f4 = t & 31;
            int rr = row0 + r;
            uint2 hv = make_uint2(0, 0);
            if (rr < nrows) {
                if (in_half) {
                    hv = *reinterpret_cast<const uint2*>(Xh + (size_t)rr * 128 + f4 * 4);
                } else {
                    float4 xv = reinterpret_cast<const float4*>(Xf)[(size_t)rr * 32 + f4];
                    __half2* hp = reinterpret_cast<__half2*>(&hv);
                    hp[0] = __floats2half2_rn(xv.x, xv.y);
                    hp[1] = __floats2half2_rn(xv.z, xv.w);
                }
            }
            int byte = (r * 256 + f4 * 8) ^ ((r & 7) << 4);
            *reinterpret_cast<uint2*>(Alds + byte) = hv;
        }
        __syncthreads();
        half8_t afr[4];
        #pragma unroll
        for (int kb = 0; kb < 4; ++kb) {
            int byte = (rloc * 256 + kb * 64 + ksub) ^ ((rloc & 7) << 4);
            afr[kb] = *reinterpret_cast<half8_t*>(Alds + byte);
        }
        floatx4 acc[8];
        #pragma unroll
        for (int nt = 0; nt < 8; ++nt) {
            int n = nt * 16 + col16;
            floatx4 a = {0.f, 0.f, 0.f, 0.f};
            #pragma unroll
            for (int kb = 0; kb < 4; ++kb) {
                int byte = (n * 256 + kb * 64 + ksub) ^ ((n & 7) << 4);
                half8_t bfr = *reinterpret_cast<half8_t*>(Wlds + byte);
                a = __builtin_amdgcn_mfma_f32_16x16x32_f16(afr[kb], bfr, a, 0, 0, 0);
            }
            acc[nt] = a;
        }
        // epilogue: D row=(lane>>4)*4+reg, col=nt*16+(lane&15)
        float ps[4][4], pd[4][4];   // [reg][head]
        #pragma unroll
        for (int reg = 0; reg < 4; ++reg)
            #pragma unroll
            for (int h = 0; h < 4; ++h) {
                ps[reg][h] = acc[2*h][reg] * Asv[2*h] + acc[2*h+1][reg] * Asv[2*h+1];
                pd[reg][h] = acc[2*h][reg] * Adv[2*h] + acc[2*h+1][reg] * Adv[2*h+1];
            }
        #pragma unroll
        for (int m = 1; m <= 8; m <<= 1)
            #pragma unroll
            for (int reg = 0; reg < 4; ++reg)
                #pragma unroll
                for (int h = 0; h < 4; ++h) {
                    ps[reg][h] += __shfl_xor(ps[reg][h], m);
                    pd[reg][h] += __shfl_xor(pd[reg][h], m);
                }
        int rbase = row0 + wv_ * 16 + (lane >> 4) * 4;
        #pragma unroll
        for (int reg = 0; reg < 4; ++reg) {
            int grow = rbase + reg;
            if (grow < nrows) {
                #pragma unroll
                for (int nt = 0; nt < 8; ++nt)
                    H16[(size_t)grow * 128 + nt * 16 + col16] = __float2half(acc[nt][reg]);
                if (col16 == 0) {
                    *reinterpret_cast<float4*>(as_out + (size_t)grow * 4) =
                        make_float4(ps[reg][0], ps[reg][1], ps[reg][2], ps[reg][3]);
                    *reinterpret_cast<float4*>(ad_out + (size_t)grow * 4) =
                        make_float4(pd[reg][0], pd[reg][1], pd[reg][2], pd[reg][3]);
                }
            }
        }
    }
}

// ---------------- bucketed two-phase sort (packed records) -----------------
__global__ __launch_bounds__(1024) void bucket_hist(const int* __restrict__ dst,
                                                    int* __restrict__ counts) {
    __shared__ int hist[NB];
    int t = threadIdx.x, b = blockIdx.x;
    if (t < NB) hist[t] = 0;
    __syncthreads();
    int s = b * CHUNK;
    for (int i = t; i < CHUNK; i += 1024)
        atomicAdd(&hist[dst[s + i] >> 8], 1);
    __syncthreads();
    if (t < NB) counts[t * NBLK + b] = hist[t];
}

// single-block exclusive scan of 50176 = 1024*49 values
__global__ __launch_bounds__(1024) void scan_all(const int* __restrict__ counts,
                                                 int* __restrict__ start) {
    __shared__ int sh[1024];
    int t = threadIdx.x;
    int base = t * 49;
    int sum = 0;
    for (int i = 0; i < 49; ++i) sum += counts[base + i];
    sh[t] = sum;
    __syncthreads();
    for (int off = 1; off < 1024; off <<= 1) {
        int v = (t >= off) ? sh[t - off] : 0;
        __syncthreads();
        sh[t] += v;
        __syncthreads();
    }
    int run = sh[t] - sum;   // exclusive prefix of this thread's chunk
    for (int i = 0; i < 49; ++i) {
        int c = counts[base + i];
        start[base + i] = run;
        run += c;
    }
}

__global__ __launch_bounds__(1024) void bucket_scatter(const int* __restrict__ src,
                                                       const int* __restrict__ dst,
                                                       const int* __restrict__ start,
                                                       int* __restrict__ bucketed) {
    __shared__ int cur[NB];
    int t = threadIdx.x, b = blockIdx.x;
    if (t < NB) cur[t] = start[t * NBLK + b];
    __syncthreads();
    int s = b * CHUNK;
    for (int i = t; i < CHUNK; i += 1024) {
        int d = dst[s + i];
        int p = atomicAdd(&cur[d >> 8], 1);
        bucketed[p] = (src[s + i] << 8) | (d & 255);   // src < 65536
    }
}

__global__ __launch_bounds__(1024) void bucket_sort(const int* __restrict__ bucketed,
                                                    const int* __restrict__ start,
                                                    int* __restrict__ sorted_packed,
                                                    int* __restrict__ off) {
    __shared__ int cnt[256], scn[256], cur[256];
    int t = threadIdx.x, k = blockIdx.x;
    int base = start[k * NBLK];
    int end = (k + 1 < NB) ? start[(k + 1) * NBLK] : N_EDGES;
    int m = end - base;
    if (t < 256) cnt[t] = 0;
    __syncthreads();
    for (int i = t; i < m; i += 1024)
        atomicAdd(&cnt[bucketed[base + i] & 255], 1);
    __syncthreads();
    if (t < 256) scn[t] = cnt[t];
    __syncthreads();
    for (int o = 1; o < 256; o <<= 1) {
        int v = (t < 256 && t >= o) ? scn[t - o] : 0;
        __syncthreads();
        if (t < 256) scn[t] += v;
        __syncthreads();
    }
    if (t < 256) {
        int excl = scn[t] - cnt[t];
        cur[t] = base + excl;
        int node = k * 256 + t;
        if (node <= N_NODES) off[node] = base + excl;
    }
    __syncthreads();
    for (int i = t; i < m; i += 1024) {
        int rec = bucketed[base + i];
        int p = atomicAdd(&cur[rec & 255], 1);
        sorted_packed[p] = rec;
    }
}

// ---- fused weights + aggregate: 1 wave/node, 16 lanes/edge, 8 cols/lane ---
__global__ __launch_bounds__(256) void gat_aggregate_f(const __half* __restrict__ H16,
                                                       const int* __restrict__ off,
                                                       const int* __restrict__ packed,
                                                       const float* __restrict__ asb,
                                                       const float* __restrict__ adb,
                                                       const float* __restrict__ bias,
                                                       float* __restrict__ OUTF,
                                                       __half* __restrict__ OUTH,
                                                       int n, int mode /*1: relu+f16, 0: f32*/) {
    int wid = (blockIdx.x * 256 + threadIdx.x) >> 6;
    int lane = threadIdx.x & 63;
    if (wid >= n) return;
    int s = off[wid], e = off[wid + 1];
    int q = lane >> 4;            // which edge of the 4-group
    int sub = lane & 15;          // 16B chunk of the row (8 cols)
    int head = sub >> 2;
    int sub16 = sub * 16;
    float adv = adb[(size_t)wid * 4 + head];   // wave-constant per head-slice
    const char* Hc = reinterpret_cast<const char*>(H16);
    const char* Ac = reinterpret_cast<const char*>(asb);
    float acc[8] = {0, 0, 0, 0, 0, 0, 0, 0};
    float den = 0.f;
    for (int i = s; i < e; i += 8) {
        int ia = i + q, ib = ia + 4;
        bool va = ia < e, vb = ib < e;
        int ja = va ? ia : s, jb = vb ? ib : s;
        int ra = packed[ja], rb = packed[jb];
        int ba = ra & 0xFFFFFF00, bb = rb & 0xFFFFFF00;  // src*256 (H row bytes)
        float sa = *reinterpret_cast<const float*>(Ac + (ba >> 4) + head * 4);
        float sb = *reinterpret_cast<const float*>(Ac + (bb >> 4) + head * 4);
        uint4 ha = *reinterpret_cast<const uint4*>(Hc + ba + sub16);
        uint4 hb = *reinterpret_cast<const uint4*>(Hc + bb + sub16);
        float ea = sa + adv; ea = fmaxf(ea, 0.2f * ea);
        float eb = sb + adv; eb = fmaxf(eb, 0.2f * eb);
        float wa = va ? __expf(ea) : 0.f;
        float wb = vb ? __expf(eb) : 0.f;
        const __half2* pa = reinterpret_cast<const __half2*>(&ha);
        const __half2* pb = reinterpret_cast<const __half2*>(&hb);
        #pragma unroll
        for (int j = 0; j < 4; ++j) {
            float2 fa = __half22float2(pa[j]);
            float2 fb = __half22float2(pb[j]);
            acc[2*j]   += wa * fa.x + wb * fb.x;
            acc[2*j+1] += wa * fa.y + wb * fb.y;
        }
        den += wa + wb;
    }
    #pragma unroll
    for (int j = 0; j < 8; ++j) acc[j] += __shfl_xor(acc[j], 16);
    den += __shfl_xor(den, 16);
    #pragma unroll
    for (int j = 0; j < 8; ++j) acc[j] += __shfl_xor(acc[j], 32);
    den += __shfl_xor(den, 32);
    if (q == 0) {
        float inv = den > 0.f ? 1.f / den : 0.f;
        float4 b0 = *reinterpret_cast<const float4*>(bias + sub * 8);
        float4 b1 = *reinterpret_cast<const float4*>(bias + sub * 8 + 4);
        float o[8];
        o[0] = acc[0]*inv + b0.x; o[1] = acc[1]*inv + b0.y;
        o[2] = acc[2]*inv + b0.z; o[3] = acc[3]*inv + b0.w;
        o[4] = acc[4]*inv + b1.x; o[5] = acc[5]*inv + b1.y;
        o[6] = acc[6]*inv + b1.z; o[7] = acc[7]*inv + b1.w;
        if (mode) {
            uint4 u;
            __half2* up = reinterpret_cast<__half2*>(&u);
            #pragma unroll
            for (int j = 0; j < 4; ++j)
                up[j] = __floats2half2_rn(fmaxf(o[2*j], 0.f), fmaxf(o[2*j+1], 0.f));
            *reinterpret_cast<uint4*>(OUTH + (size_t)wid * 128 + sub * 8) = u;
        } else {
            *reinterpret_cast<float4*>(OUTF + (size_t)wid * 128 + sub * 8) =
                make_float4(o[0], o[1], o[2], o[3]);
            *reinterpret_cast<float4*>(OUTF + (size_t)wid * 128 + sub * 8 + 4) =
                make_float4(o[4], o[5], o[6], o[7]);
        }
    }
}

// ---------------------------------------------------------------------------
extern "C" void kernel_launch(void* const* d_in, const int* in_sizes, int n_in,
                              void* d_out, int out_size, void* d_ws, size_t ws_size,
                              hipStream_t stream) {
    const float* x        = (const float*)d_in[0];
    const int*   edge     = (const int*)d_in[1];
    const float* W0       = (const float*)d_in[2];
    const float* att_src0 = (const float*)d_in[3];
    const float* att_dst0 = (const float*)d_in[4];
    const float* b0       = (const float*)d_in[5];
    const float* W1       = (const float*)d_in[6];
    const float* att_src1 = (const float*)d_in[7];
    const float* att_dst1 = (const float*)d_in[8];
    const float* b1       = (const float*)d_in[9];
    const int* src = edge;
    const int* dst = edge + N_EDGES;
    float* out = (float*)d_out;

    char* ws = (char*)d_ws;
    size_t o = 0;
    auto alloc = [&](size_t bytes) { char* p = ws + o; o += (bytes + 255) & ~(size_t)255; return p; };
    __half* H16   = (__half*)alloc((size_t)N_NODES * 128 * 2);    // 12.8 MB (persistent)
    float* asb    = (float*)alloc((size_t)N_NODES * 4 * 4);
    float* adb    = (float*)alloc((size_t)N_NODES * 4 * 4);
    int*   off    = (int*)alloc((size_t)(N_NODES + 1) * 4);
    int*   sorted = (int*)alloc((size_t)N_EDGES * 4);             // 6.4 MB (persistent)
    // overlay: sort temps, later reused as the f16 layer-0 output
    size_t mark = o;
    int*   counts = (int*)alloc((size_t)SCAN_N * 4);
    int*   start  = (int*)alloc((size_t)SCAN_N * 4);
    int*   bucketed = (int*)alloc((size_t)N_EDGES * 4);           // 6.4 MB
    __half* h1_16 = (__half*)(ws + mark);                         // 12.8 MB, aliases temps

    // ---- sort edges by dst (packed records; shared by both layers) ----
    bucket_hist<<<NBLK, 1024, 0, stream>>>(dst, counts);
    scan_all<<<1, 1024, 0, stream>>>(counts, start);
    bucket_scatter<<<NBLK, 1024, 0, stream>>>(src, dst, start, bucketed);
    bucket_sort<<<NB, 1024, 0, stream>>>(bucketed, start, sorted, off);

    int agg_blocks = (N_NODES + 3) / 4;

    // ---- layer 0 ----
    gemm_mfma<<<256, 256, 0, stream>>>(x, (const __half*)nullptr, 0, W0, att_src0, att_dst0,
                                       H16, asb, adb, N_NODES);
    gat_aggregate_f<<<agg_blocks, 256, 0, stream>>>(H16, off, sorted, asb, adb, b0,
                                                    (float*)nullptr, h1_16, N_NODES, 1);

    // ---- layer 1 ----
    gemm_mfma<<<256, 256, 0, stream>>>((const float*)nullptr, h1_16, 1, W1, att_src1, att_dst1,
                                       H16, asb, adb, N_NODES);
    gat_aggregate_f<<<agg_blocks, 256, 0, stream>>>(H16, off, sorted, asb, adb, b1,
                                                    out, (__half*)nullptr, N_NODES, 0);
}

// Round 7
// 212.921 us; speedup vs baseline: 3.2384x; 1.0447x over previous
//
#include <hip/hip_runtime.h>
#include <hip/hip_fp16.h>

#define N_NODES 50000
#define N_EDGES 1600000
#define NB 196                  // buckets: dst>>8
#define NBLK 256                // phase-A blocks
#define CHUNK (N_EDGES / NBLK)  // 6250
#define SCAN_N (NB * NBLK)      // 50176 = 1024*49
#define GEMM_BLOCKS 256

typedef _Float16 half8_t __attribute__((ext_vector_type(8)));
typedef _Float16 half2_t __attribute__((ext_vector_type(2)));
typedef float floatx4 __attribute__((ext_vector_type(4)));

#if defined(__has_builtin)
#  if __has_builtin(__builtin_amdgcn_fdot2)
#    define HAS_FDOT2 1
#  endif
#endif
#ifndef HAS_FDOT2
#  define HAS_FDOT2 0
#endif

// ---- MFMA f16 GEMM (persistent) + fused score epilogue (+optional hist) ---
__global__ __launch_bounds__(256) void gemm_mfma(const float* __restrict__ Xf,
                                                 const __half* __restrict__ Xh,
                                                 int in_half,
                                                 const float* __restrict__ W,
                                                 const float* __restrict__ att_s,
                                                 const float* __restrict__ att_d,
                                                 __half* __restrict__ H16,
                                                 float* __restrict__ as_out,
                                                 float* __restrict__ ad_out, int nrows,
                                                 const int* __restrict__ hist_dst,
                                                 int* __restrict__ hist_counts) {
    __shared__ __align__(16) char lds[49152];   // A:[0,16K) Wt:[16K,48K)
    int t = threadIdx.x;
    // ---- histogram role (independent work fused into this dispatch) ----
    if (hist_counts != nullptr && blockIdx.x >= GEMM_BLOCKS) {
        int* hist = reinterpret_cast<int*>(lds);
        int b = blockIdx.x - GEMM_BLOCKS;
        for (int i = t; i < NB; i += 256) hist[i] = 0;
        __syncthreads();
        int s = b * CHUNK;
        for (int i = t; i < CHUNK; i += 256)
            atomicAdd(&hist[hist_dst[s + i] >> 8], 1);
        __syncthreads();
        for (int i = t; i < NB; i += 256) hist_counts[i * NBLK + b] = hist[i];
        return;
    }
    // ---- GEMM role ----
    char* Alds = lds;
    char* Wlds = lds + 16384;
    int lane = t & 63, wv_ = t >> 6;
    for (int p = 0; p < 16; ++p) {           // stage Wt[n][k] f16 swizzled, once
        int flat = p * 256 + t;
        int k = flat >> 5;
        int n0 = (flat & 31) * 4;
        float4 wv = reinterpret_cast<const float4*>(W)[flat];
        const float* wf = reinterpret_cast<const float*>(&wv);
        #pragma unroll
        for (int i = 0; i < 4; ++i) {
            int n = n0 + i;
            int byte = (n * 256 + k * 2) ^ ((n & 7) << 4);
            *reinterpret_cast<__half*>(Wlds + byte) = __float2half(wf[i]);
        }
    }
    int col16 = lane & 15;
    float Asv[8], Adv[8];
    #pragma unroll
    for (int nt = 0; nt < 8; ++nt) {
        Asv[nt] = att_s[nt * 16 + col16];
        Adv[nt] = att_d[nt * 16 + col16];
    }
    int ksub = (lane >> 4) * 16;
    int rloc = wv_ * 16 + col16;
    int ntiles = (nrows + 63) / 64;
    for (int tile = blockIdx.x; tile < ntiles; tile += GEMM_BLOCKS) {
        int row0 = tile * 64;
        __syncthreads();
        for (int p = 0; p < 8; ++p) {
            int r = p * 8 + (t >> 5);
            int f4 = t & 31;
            int rr = row0 + r;
            uint2 hv = make_uint2(0, 0);
            if (rr < nrows) {
                if (in_half) {
                    hv = *reinterpret_cast<const uint2*>(Xh + (size_t)rr * 128 + f4 * 4);
                } else {
                    float4 xv = reinterpret_cast<const float4*>(Xf)[(size_t)rr * 32 + f4];
                    __half2* hp = reinterpret_cast<__half2*>(&hv);
                    hp[0] = __floats2half2_rn(xv.x, xv.y);
                    hp[1] = __floats2half2_rn(xv.z, xv.w);
                }
            }
            int byte = (r * 256 + f4 * 8) ^ ((r & 7) << 4);
            *reinterpret_cast<uint2*>(Alds + byte) = hv;
        }
        __syncthreads();
        half8_t afr[4];
        #pragma unroll
        for (int kb = 0; kb < 4; ++kb) {
            int byte = (rloc * 256 + kb * 64 + ksub) ^ ((rloc & 7) << 4);
            afr[kb] = *reinterpret_cast<half8_t*>(Alds + byte);
        }
        floatx4 acc[8];
        #pragma unroll
        for (int nt = 0; nt < 8; ++nt) {
            int n = nt * 16 + col16;
            floatx4 a = {0.f, 0.f, 0.f, 0.f};
            #pragma unroll
            for (int kb = 0; kb < 4; ++kb) {
                int byte = (n * 256 + kb * 64 + ksub) ^ ((n & 7) << 4);
                half8_t bfr = *reinterpret_cast<half8_t*>(Wlds + byte);
                a = __builtin_amdgcn_mfma_f32_16x16x32_f16(afr[kb], bfr, a, 0, 0, 0);
            }
            acc[nt] = a;
        }
        float ps[4][4], pd[4][4];
        #pragma unroll
        for (int reg = 0; reg < 4; ++reg)
            #pragma unroll
            for (int h = 0; h < 4; ++h) {
                ps[reg][h] = acc[2*h][reg] * Asv[2*h] + acc[2*h+1][reg] * Asv[2*h+1];
                pd[reg][h] = acc[2*h][reg] * Adv[2*h] + acc[2*h+1][reg] * Adv[2*h+1];
            }
        #pragma unroll
        for (int m = 1; m <= 8; m <<= 1)
            #pragma unroll
            for (int reg = 0; reg < 4; ++reg)
                #pragma unroll
                for (int h = 0; h < 4; ++h) {
                    ps[reg][h] += __shfl_xor(ps[reg][h], m);
                    pd[reg][h] += __shfl_xor(pd[reg][h], m);
                }
        int rbase = row0 + wv_ * 16 + (lane >> 4) * 4;
        #pragma unroll
        for (int reg = 0; reg < 4; ++reg) {
            int grow = rbase + reg;
            if (grow < nrows) {
                #pragma unroll
                for (int nt = 0; nt < 8; ++nt)
                    H16[(size_t)grow * 128 + nt * 16 + col16] = __float2half(acc[nt][reg]);
                if (col16 == 0) {
                    *reinterpret_cast<float4*>(as_out + (size_t)grow * 4) =
                        make_float4(ps[reg][0], ps[reg][1], ps[reg][2], ps[reg][3]);
                    *reinterpret_cast<float4*>(ad_out + (size_t)grow * 4) =
                        make_float4(pd[reg][0], pd[reg][1], pd[reg][2], pd[reg][3]);
                }
            }
        }
    }
}

// single-block exclusive scan of 50176 = 1024*49 values
__global__ __launch_bounds__(1024) void scan_all(const int* __restrict__ counts,
                                                 int* __restrict__ start) {
    __shared__ int sh[1024];
    int t = threadIdx.x;
    int base = t * 49;
    int sum = 0;
    for (int i = 0; i < 49; ++i) sum += counts[base + i];
    sh[t] = sum;
    __syncthreads();
    for (int off = 1; off < 1024; off <<= 1) {
        int v = (t >= off) ? sh[t - off] : 0;
        __syncthreads();
        sh[t] += v;
        __syncthreads();
    }
    int run = sh[t] - sum;
    for (int i = 0; i < 49; ++i) {
        int c = counts[base + i];
        start[base + i] = run;
        run += c;
    }
}

__global__ __launch_bounds__(1024) void bucket_scatter(const int* __restrict__ src,
                                                       const int* __restrict__ dst,
                                                       const int* __restrict__ start,
                                                       int* __restrict__ bucketed) {
    __shared__ int cur[NB];
    int t = threadIdx.x, b = blockIdx.x;
    if (t < NB) cur[t] = start[t * NBLK + b];
    __syncthreads();
    int s = b * CHUNK;
    for (int i = t; i < CHUNK; i += 1024) {
        int d = dst[s + i];
        int p = atomicAdd(&cur[d >> 8], 1);
        bucketed[p] = (src[s + i] << 8) | (d & 255);   // src < 65536
    }
}

__global__ __launch_bounds__(1024) void bucket_sort(const int* __restrict__ bucketed,
                                                    const int* __restrict__ start,
                                                    int* __restrict__ sorted_packed,
                                                    int* __restrict__ off) {
    __shared__ int cnt[256], scn[256], cur[256];
    int t = threadIdx.x, k = blockIdx.x;
    int base = start[k * NBLK];
    int end = (k + 1 < NB) ? start[(k + 1) * NBLK] : N_EDGES;
    int m = end - base;
    if (t < 256) cnt[t] = 0;
    __syncthreads();
    for (int i = t; i < m; i += 1024)
        atomicAdd(&cnt[bucketed[base + i] & 255], 1);
    __syncthreads();
    if (t < 256) scn[t] = cnt[t];
    __syncthreads();
    for (int o = 1; o < 256; o <<= 1) {
        int v = (t < 256 && t >= o) ? scn[t - o] : 0;
        __syncthreads();
        if (t < 256) scn[t] += v;
        __syncthreads();
    }
    if (t < 256) {
        int excl = scn[t] - cnt[t];
        cur[t] = base + excl;
        int node = k * 256 + t;
        if (node <= N_NODES) off[node] = base + excl;
    }
    __syncthreads();
    for (int i = t; i < m; i += 1024) {
        int rec = bucketed[base + i];
        int p = atomicAdd(&cur[rec & 255], 1);
        sorted_packed[p] = rec;
    }
}

// ---- fused weights + aggregate v2: prefetched indices, fdot2 inner loop ---
__global__ __launch_bounds__(256) void gat_aggregate_v2(const __half* __restrict__ H16,
                                                        const int* __restrict__ off,
                                                        const int* __restrict__ packed,
                                                        const float* __restrict__ asb,
                                                        const float* __restrict__ adb,
                                                        const float* __restrict__ bias,
                                                        float* __restrict__ OUTF,
                                                        __half* __restrict__ OUTH,
                                                        int n, int mode) {
    int wid = (blockIdx.x * 256 + threadIdx.x) >> 6;
    int lane = threadIdx.x & 63;
    if (wid >= n) return;
    int s = off[wid], e = off[wid + 1];
    int q = lane >> 4;            // edge slot within 4-group
    int sub = lane & 15;          // 16B chunk of the 256B row
    int head4 = (sub >> 2) * 4;   // byte offset of this head's score
    int sub16 = sub * 16;
    float adv = adb[(size_t)wid * 4 + (sub >> 2)];
    const char* Hc = reinterpret_cast<const char*>(H16);
    const char* Ac = reinterpret_cast<const char*>(asb);
    float acc[8] = {0, 0, 0, 0, 0, 0, 0, 0};
    float den = 0.f;
    if (s < e) {
        // preload slot indices + scores for the first iteration
        int ia = s + q, ib = ia + 4;
        int ja = ia < e ? ia : s, jb = ib < e ? ib : s;
        int ra = packed[ja] & 0xFFFFFF00;      // src*256 = byte offset of H row
        int rb = packed[jb] & 0xFFFFFF00;
        float sa = *reinterpret_cast<const float*>(Ac + (ra >> 4) + head4);
        float sb = *reinterpret_cast<const float*>(Ac + (rb >> 4) + head4);
        for (int i = s; i < e; i += 8) {
            uint4 ha = *reinterpret_cast<const uint4*>(Hc + ra + sub16);
            uint4 hb = *reinterpret_cast<const uint4*>(Hc + rb + sub16);
            bool va = (i + q) < e, vb = (i + q + 4) < e;
            float ea = sa + adv; ea = fmaxf(ea, 0.2f * ea);
            float eb = sb + adv; eb = fmaxf(eb, 0.2f * eb);
            float wa = va ? __expf(ea) : 0.f;
            float wb = vb ? __expf(eb) : 0.f;
            // prefetch next iteration's records + scores (clamped, safe)
            int ia2 = i + 8 + q, ib2 = ia2 + 4;
            int ja2 = ia2 < e ? ia2 : s, jb2 = ib2 < e ? ib2 : s;
            ra = packed[ja2] & 0xFFFFFF00;
            rb = packed[jb2] & 0xFFFFFF00;
            sa = *reinterpret_cast<const float*>(Ac + (ra >> 4) + head4);
            sb = *reinterpret_cast<const float*>(Ac + (rb >> 4) + head4);
            den += wa + wb;
#if HAS_FDOT2
            half2_t w01 = __builtin_bit_cast(half2_t, __builtin_amdgcn_cvt_pkrtz(wa, wb));
            const uint* hau = reinterpret_cast<const uint*>(&ha);
            const uint* hbu = reinterpret_cast<const uint*>(&hb);
            #pragma unroll
            for (int j = 0; j < 4; ++j) {
                uint p0 = __builtin_amdgcn_perm(hbu[j], hau[j], 0x05040100u);
                uint p1 = __builtin_amdgcn_perm(hbu[j], hau[j], 0x07060302u);
                acc[2*j]   = __builtin_amdgcn_fdot2(__builtin_bit_cast(half2_t, p0), w01, acc[2*j],   false);
                acc[2*j+1] = __builtin_amdgcn_fdot2(__builtin_bit_cast(half2_t, p1), w01, acc[2*j+1], false);
            }
#else
            const __half2* pa = reinterpret_cast<const __half2*>(&ha);
            const __half2* pb = reinterpret_cast<const __half2*>(&hb);
            #pragma unroll
            for (int j = 0; j < 4; ++j) {
                float2 fa = __half22float2(pa[j]);
                float2 fb = __half22float2(pb[j]);
                acc[2*j]   += wa * fa.x + wb * fb.x;
                acc[2*j+1] += wa * fa.y + wb * fb.y;
            }
#endif
        }
    }
    #pragma unroll
    for (int j = 0; j < 8; ++j) acc[j] += __shfl_xor(acc[j], 16);
    den += __shfl_xor(den, 16);
    #pragma unroll
    for (int j = 0; j < 8; ++j) acc[j] += __shfl_xor(acc[j], 32);
    den += __shfl_xor(den, 32);
    if (q == 0) {
        float inv = den > 0.f ? 1.f / den : 0.f;
        float4 b0 = *reinterpret_cast<const float4*>(bias + sub * 8);
        float4 b1 = *reinterpret_cast<const float4*>(bias + sub * 8 + 4);
        float o[8];
        o[0] = acc[0]*inv + b0.x; o[1] = acc[1]*inv + b0.y;
        o[2] = acc[2]*inv + b0.z; o[3] = acc[3]*inv + b0.w;
        o[4] = acc[4]*inv + b1.x; o[5] = acc[5]*inv + b1.y;
        o[6] = acc[6]*inv + b1.z; o[7] = acc[7]*inv + b1.w;
        if (mode) {
            uint4 u;
            __half2* up = reinterpret_cast<__half2*>(&u);
            #pragma unroll
            for (int j = 0; j < 4; ++j)
                up[j] = __floats2half2_rn(fmaxf(o[2*j], 0.f), fmaxf(o[2*j+1], 0.f));
            *reinterpret_cast<uint4*>(OUTH + (size_t)wid * 128 + sub * 8) = u;
        } else {
            *reinterpret_cast<float4*>(OUTF + (size_t)wid * 128 + sub * 8) =
                make_float4(o[0], o[1], o[2], o[3]);
            *reinterpret_cast<float4*>(OUTF + (size_t)wid * 128 + sub * 8 + 4) =
                make_float4(o[4], o[5], o[6], o[7]);
        }
    }
}

// ---------------------------------------------------------------------------
extern "C" void kernel_launch(void* const* d_in, const int* in_sizes, int n_in,
                              void* d_out, int out_size, void* d_ws, size_t ws_size,
                              hipStream_t stream) {
    const float* x        = (const float*)d_in[0];
    const int*   edge     = (const int*)d_in[1];
    const float* W0       = (const float*)d_in[2];
    const float* att_src0 = (const float*)d_in[3];
    const float* att_dst0 = (const float*)d_in[4];
    const float* b0       = (const float*)d_in[5];
    const float* W1       = (const float*)d_in[6];
    const float* att_src1 = (const float*)d_in[7];
    const float* att_dst1 = (const float*)d_in[8];
    const float* b1       = (const float*)d_in[9];
    const int* src = edge;
    const int* dst = edge + N_EDGES;
    float* out = (float*)d_out;

    char* ws = (char*)d_ws;
    size_t o = 0;
    auto alloc = [&](size_t bytes) { char* p = ws + o; o += (bytes + 255) & ~(size_t)255; return p; };
    __half* H16   = (__half*)alloc((size_t)N_NODES * 128 * 2);    // 12.8 MB (persistent)
    float* asb    = (float*)alloc((size_t)N_NODES * 4 * 4);
    float* adb    = (float*)alloc((size_t)N_NODES * 4 * 4);
    int*   off    = (int*)alloc((size_t)(N_NODES + 1) * 4);
    int*   sorted = (int*)alloc((size_t)N_EDGES * 4);             // 6.4 MB (persistent)
    // overlay: sort temps, later reused as the f16 layer-0 output
    size_t mark = o;
    int*   counts = (int*)alloc((size_t)SCAN_N * 4);
    int*   start  = (int*)alloc((size_t)SCAN_N * 4);
    int*   bucketed = (int*)alloc((size_t)N_EDGES * 4);           // 6.4 MB
    __half* h1_16 = (__half*)(ws + mark);                         // 12.8 MB, aliases temps

    int agg_blocks = N_NODES / 4;   // 12500, exact

    // ---- layer-0 GEMM fused with edge histogram (independent work) ----
    gemm_mfma<<<GEMM_BLOCKS + NBLK, 256, 0, stream>>>(x, (const __half*)nullptr, 0,
                                                      W0, att_src0, att_dst0,
                                                      H16, asb, adb, N_NODES, dst, counts);
    // ---- remaining sort chain ----
    scan_all<<<1, 1024, 0, stream>>>(counts, start);
    bucket_scatter<<<NBLK, 1024, 0, stream>>>(src, dst, start, bucketed);
    bucket_sort<<<NB, 1024, 0, stream>>>(bucketed, start, sorted, off);

    // ---- layer 0 aggregate (writes f16 + relu) ----
    gat_aggregate_v2<<<agg_blocks, 256, 0, stream>>>(H16, off, sorted, asb, adb, b0,
                                                     (float*)nullptr, h1_16, N_NODES, 1);

    // ---- layer 1 ----
    gemm_mfma<<<GEMM_BLOCKS, 256, 0, stream>>>((const float*)nullptr, h1_16, 1,
                                               W1, att_src1, att_dst1,
                                               H16, asb, adb, N_NODES,
                                               (const int*)nullptr, (int*)nullptr);
    gat_aggregate_v2<<<agg_blocks, 256, 0, stream>>>(H16, off, sorted, asb, adb, b1,
                                                     out, (__half*)nullptr, N_NODES, 0);
}

// Round 8
// 202.849 us; speedup vs baseline: 3.3992x; 1.0497x over previous
//
#include <hip/hip_runtime.h>
#include <hip/hip_fp16.h>

#define N_NODES 50000
#define N_EDGES 1600000
#define NB 196                  // buckets: dst>>8
#define NBLK 256                // scatter blocks
#define CHUNK (N_EDGES / NBLK)  // 6250
#define GEMM_BLOCKS 256

typedef _Float16 half8_t __attribute__((ext_vector_type(8)));
typedef _Float16 half2_t __attribute__((ext_vector_type(2)));
typedef float floatx4 __attribute__((ext_vector_type(4)));

#if defined(__has_builtin)
#  if __has_builtin(__builtin_amdgcn_fdot2)
#    define HAS_FDOT2 1
#  endif
#endif
#ifndef HAS_FDOT2
#  define HAS_FDOT2 0
#endif

// ---- MFMA f16 GEMM (persistent) + fused score epilogue (+optional hist) ---
__global__ __launch_bounds__(256) void gemm_mfma(const float* __restrict__ Xf,
                                                 const __half* __restrict__ Xh,
                                                 int in_half,
                                                 const float* __restrict__ W,
                                                 const float* __restrict__ att_s,
                                                 const float* __restrict__ att_d,
                                                 __half* __restrict__ H16,
                                                 float* __restrict__ as_out,
                                                 float* __restrict__ ad_out, int nrows,
                                                 const int* __restrict__ hist_dst,
                                                 int* __restrict__ hist_totals) {
    __shared__ __align__(16) char lds[49152];   // A:[0,16K) Wt:[16K,48K)
    int t = threadIdx.x;
    // ---- histogram role: per-block LDS hist -> global 196 totals ----
    if (hist_totals != nullptr && blockIdx.x >= GEMM_BLOCKS) {
        int* hist = reinterpret_cast<int*>(lds);
        int b = blockIdx.x - GEMM_BLOCKS;
        for (int i = t; i < NB; i += 256) hist[i] = 0;
        __syncthreads();
        int s = b * CHUNK;
        for (int i = t; i < CHUNK; i += 256)
            atomicAdd(&hist[hist_dst[s + i] >> 8], 1);
        __syncthreads();
        for (int i = t; i < NB; i += 256)
            if (hist[i]) atomicAdd(&hist_totals[i], hist[i]);
        return;
    }
    // ---- GEMM role ----
    char* Alds = lds;
    char* Wlds = lds + 16384;
    int lane = t & 63, wv_ = t >> 6;
    for (int p = 0; p < 16; ++p) {           // stage Wt[n][k] f16 swizzled, once
        int flat = p * 256 + t;
        int k = flat >> 5;
        int n0 = (flat & 31) * 4;
        float4 wv = reinterpret_cast<const float4*>(W)[flat];
        const float* wf = reinterpret_cast<const float*>(&wv);
        #pragma unroll
        for (int i = 0; i < 4; ++i) {
            int n = n0 + i;
            int byte = (n * 256 + k * 2) ^ ((n & 7) << 4);
            *reinterpret_cast<__half*>(Wlds + byte) = __float2half(wf[i]);
        }
    }
    int col16 = lane & 15;
    float Asv[8], Adv[8];
    #pragma unroll
    for (int nt = 0; nt < 8; ++nt) {
        Asv[nt] = att_s[nt * 16 + col16];
        Adv[nt] = att_d[nt * 16 + col16];
    }
    int ksub = (lane >> 4) * 16;
    int rloc = wv_ * 16 + col16;
    int ntiles = (nrows + 63) / 64;
    for (int tile = blockIdx.x; tile < ntiles; tile += GEMM_BLOCKS) {
        int row0 = tile * 64;
        __syncthreads();
        for (int p = 0; p < 8; ++p) {
            int r = p * 8 + (t >> 5);
            int f4 = t & 31;
            int rr = row0 + r;
            uint2 hv = make_uint2(0, 0);
            if (rr < nrows) {
                if (in_half) {
                    hv = *reinterpret_cast<const uint2*>(Xh + (size_t)rr * 128 + f4 * 4);
                } else {
                    float4 xv = reinterpret_cast<const float4*>(Xf)[(size_t)rr * 32 + f4];
                    __half2* hp = reinterpret_cast<__half2*>(&hv);
                    hp[0] = __floats2half2_rn(xv.x, xv.y);
                    hp[1] = __floats2half2_rn(xv.z, xv.w);
                }
            }
            int byte = (r * 256 + f4 * 8) ^ ((r & 7) << 4);
            *reinterpret_cast<uint2*>(Alds + byte) = hv;
        }
        __syncthreads();
        half8_t afr[4];
        #pragma unroll
        for (int kb = 0; kb < 4; ++kb) {
            int byte = (rloc * 256 + kb * 64 + ksub) ^ ((rloc & 7) << 4);
            afr[kb] = *reinterpret_cast<half8_t*>(Alds + byte);
        }
        floatx4 acc[8];
        #pragma unroll
        for (int nt = 0; nt < 8; ++nt) {
            int n = nt * 16 + col16;
            floatx4 a = {0.f, 0.f, 0.f, 0.f};
            #pragma unroll
            for (int kb = 0; kb < 4; ++kb) {
                int byte = (n * 256 + kb * 64 + ksub) ^ ((n & 7) << 4);
                half8_t bfr = *reinterpret_cast<half8_t*>(Wlds + byte);
                a = __builtin_amdgcn_mfma_f32_16x16x32_f16(afr[kb], bfr, a, 0, 0, 0);
            }
            acc[nt] = a;
        }
        float ps[4][4], pd[4][4];
        #pragma unroll
        for (int reg = 0; reg < 4; ++reg)
            #pragma unroll
            for (int h = 0; h < 4; ++h) {
                ps[reg][h] = acc[2*h][reg] * Asv[2*h] + acc[2*h+1][reg] * Asv[2*h+1];
                pd[reg][h] = acc[2*h][reg] * Adv[2*h] + acc[2*h+1][reg] * Adv[2*h+1];
            }
        #pragma unroll
        for (int m = 1; m <= 8; m <<= 1)
            #pragma unroll
            for (int reg = 0; reg < 4; ++reg)
                #pragma unroll
                for (int h = 0; h < 4; ++h) {
                    ps[reg][h] += __shfl_xor(ps[reg][h], m);
                    pd[reg][h] += __shfl_xor(pd[reg][h], m);
                }
        int rbase = row0 + wv_ * 16 + (lane >> 4) * 4;
        #pragma unroll
        for (int reg = 0; reg < 4; ++reg) {
            int grow = rbase + reg;
            if (grow < nrows) {
                #pragma unroll
                for (int nt = 0; nt < 8; ++nt)
                    H16[(size_t)grow * 128 + nt * 16 + col16] = __float2half(acc[nt][reg]);
                if (col16 == 0) {
                    *reinterpret_cast<float4*>(as_out + (size_t)grow * 4) =
                        make_float4(ps[reg][0], ps[reg][1], ps[reg][2], ps[reg][3]);
                    *reinterpret_cast<float4*>(ad_out + (size_t)grow * 4) =
                        make_float4(pd[reg][0], pd[reg][1], pd[reg][2], pd[reg][3]);
                }
            }
        }
    }
}

// ---- phase A: LDS-reorder scatter with coalesced run writes ---------------
// Regions claimed per (bucket,block) via global cursors; only 196 totals needed.
__global__ __launch_bounds__(1024) void bucket_scatter(const int* __restrict__ src,
                                                       const int* __restrict__ dst,
                                                       const int* __restrict__ btotal,
                                                       int* __restrict__ bcursor,
                                                       int* __restrict__ bucketed) {
    __shared__ int bexcl[NB];    // exclusive global bucket base
    __shared__ int hist[NB];
    __shared__ int lstart[NB];   // exclusive LDS run start
    __shared__ int curL[NB];
    __shared__ int gbase[NB];    // claimed global run start
    __shared__ int recs[CHUNK];  // (src<<16)|dst
    __shared__ int srt[CHUNK];   // bucket-grouped
    int t = threadIdx.x, b = blockIdx.x;
    int myTot = 0;
    if (t < NB) { myTot = btotal[t]; bexcl[t] = myTot; }
    for (int i = t; i < NB; i += 1024) hist[i] = 0;
    __syncthreads();
    for (int o = 1; o < NB; o <<= 1) {           // scan of bucket totals
        int v = (t < NB && t >= o) ? bexcl[t - o] : 0;
        __syncthreads();
        if (t < NB) bexcl[t] += v;
        __syncthreads();
    }
    if (t < NB) bexcl[t] -= myTot;               // inclusive -> exclusive
    int s0 = b * CHUNK;
    for (int i = t; i < CHUNK; i += 1024) {      // load + per-block hist
        unsigned sv = (unsigned)src[s0 + i], dv = (unsigned)dst[s0 + i];
        recs[i] = (int)((sv << 16) | dv);
        atomicAdd(&hist[dv >> 8], 1);
    }
    __syncthreads();
    int myCnt = (t < NB) ? hist[t] : 0;
    if (t < NB) lstart[t] = myCnt;
    __syncthreads();
    for (int o = 1; o < NB; o <<= 1) {           // scan of block's hist
        int v = (t < NB && t >= o) ? lstart[t - o] : 0;
        __syncthreads();
        if (t < NB) lstart[t] += v;
        __syncthreads();
    }
    if (t < NB) {
        int ex = lstart[t] - myCnt;
        lstart[t] = ex;
        curL[t] = ex;
        gbase[t] = bexcl[t] + atomicAdd(&bcursor[t], myCnt);
    }
    __syncthreads();
    for (int i = t; i < CHUNK; i += 1024) {      // LDS reorder by bucket
        int r = recs[i];
        int bk = (int)(((unsigned)r & 0xFFFFu) >> 8);
        int p = atomicAdd(&curL[bk], 1);
        srt[p] = r;
    }
    __syncthreads();
    for (int p = t; p < CHUNK; p += 1024) {      // coalesced run writes
        int r = srt[p];
        unsigned d = (unsigned)r & 0xFFFFu;
        int bk = (int)(d >> 8);
        int g = gbase[bk] + (p - lstart[bk]);
        bucketed[g] = (int)((((unsigned)r >> 16) << 8) | (d & 255u));
    }
}

// ---- phase B: within-bucket counting sort by dst; emits off[] -------------
__global__ __launch_bounds__(1024) void bucket_sort(const int* __restrict__ bucketed,
                                                    const int* __restrict__ btotal,
                                                    int* __restrict__ sorted_packed,
                                                    int* __restrict__ off) {
    __shared__ int bb[NB];
    __shared__ int cnt[256], scn[256], cur[256];
    int t = threadIdx.x, k = blockIdx.x;
    if (t < NB) bb[t] = btotal[t];
    if (t < 256) cnt[t] = 0;
    __syncthreads();
    for (int o = 1; o < NB; o <<= 1) {
        int v = (t < NB && t >= o) ? bb[t - o] : 0;
        __syncthreads();
        if (t < NB) bb[t] += v;
        __syncthreads();
    }
    int base = (k == 0) ? 0 : bb[k - 1];
    int end  = bb[k];
    int m = end - base;
    for (int i = t; i < m; i += 1024)
        atomicAdd(&cnt[bucketed[base + i] & 255], 1);
    __syncthreads();
    if (t < 256) scn[t] = cnt[t];
    __syncthreads();
    for (int o = 1; o < 256; o <<= 1) {
        int v = (t < 256 && t >= o) ? scn[t - o] : 0;
        __syncthreads();
        if (t < 256) scn[t] += v;
        __syncthreads();
    }
    if (t < 256) {
        int excl = scn[t] - cnt[t];
        cur[t] = base + excl;
        int node = k * 256 + t;
        if (node <= N_NODES) off[node] = base + excl;
    }
    __syncthreads();
    for (int i = t; i < m; i += 1024) {
        int rec = bucketed[base + i];
        int p = atomicAdd(&cur[rec & 255], 1);
        sorted_packed[p] = rec;
    }
}

// ---- fused weights + aggregate v3: 16 edges/iter, 4 row-loads in flight ---
__global__ __launch_bounds__(256) void gat_aggregate_v3(const __half* __restrict__ H16,
                                                        const int* __restrict__ off,
                                                        const int* __restrict__ packed,
                                                        const float* __restrict__ asb,
                                                        const float* __restrict__ adb,
                                                        const float* __restrict__ bias,
                                                        float* __restrict__ OUTF,
                                                        __half* __restrict__ OUTH,
                                                        int n, int mode) {
    int wid = (blockIdx.x * 256 + threadIdx.x) >> 6;
    int lane = threadIdx.x & 63;
    if (wid >= n) return;
    int s = off[wid], e = off[wid + 1];
    int q = lane >> 4;            // edge slot within the 4-group
    int sub = lane & 15;          // 16B chunk of the 256B row
    int head4 = (sub >> 2) * 4;   // byte offset of this head's score
    int sub16 = sub * 16;
    float adv = adb[(size_t)wid * 4 + (sub >> 2)];
    const char* Hc = reinterpret_cast<const char*>(H16);
    const char* Ac = reinterpret_cast<const char*>(asb);
    float acc[8] = {0, 0, 0, 0, 0, 0, 0, 0};
    float den = 0.f;
    if (s < e) {
        int idx[4]; float sc[4];
        #pragma unroll
        for (int u = 0; u < 4; ++u) {
            int ii = s + q + u * 4;
            int jj = ii < e ? ii : s;
            idx[u] = packed[jj] & 0xFFFFFF00;      // src*256 = H row byte offset
            sc[u] = *reinterpret_cast<const float*>(Ac + (idx[u] >> 4) + head4);
        }
        for (int i = s; i < e; i += 16) {
            uint4 h0 = *reinterpret_cast<const uint4*>(Hc + idx[0] + sub16);
            uint4 h1 = *reinterpret_cast<const uint4*>(Hc + idx[1] + sub16);
            uint4 h2 = *reinterpret_cast<const uint4*>(Hc + idx[2] + sub16);
            uint4 h3 = *reinterpret_cast<const uint4*>(Hc + idx[3] + sub16);
            float w[4];
            #pragma unroll
            for (int u = 0; u < 4; ++u) {
                float ev = sc[u] + adv; ev = fmaxf(ev, 0.2f * ev);
                w[u] = (i + q + u * 4 < e) ? __expf(ev) : 0.f;
            }
            #pragma unroll
            for (int u = 0; u < 4; ++u) {          // prefetch next 4 slots
                int ii = i + 16 + q + u * 4;
                int jj = ii < e ? ii : s;
                idx[u] = packed[jj] & 0xFFFFFF00;
                sc[u] = *reinterpret_cast<const float*>(Ac + (idx[u] >> 4) + head4);
            }
            den += (w[0] + w[1]) + (w[2] + w[3]);
#if HAS_FDOT2
            half2_t w01 = __builtin_bit_cast(half2_t, __builtin_amdgcn_cvt_pkrtz(w[0], w[1]));
            half2_t w23 = __builtin_bit_cast(half2_t, __builtin_amdgcn_cvt_pkrtz(w[2], w[3]));
            const uint* a0 = reinterpret_cast<const uint*>(&h0);
            const uint* a1 = reinterpret_cast<const uint*>(&h1);
            const uint* a2 = reinterpret_cast<const uint*>(&h2);
            const uint* a3 = reinterpret_cast<const uint*>(&h3);
            #pragma unroll
            for (int j = 0; j < 4; ++j) {
                uint p0 = __builtin_amdgcn_perm(a1[j], a0[j], 0x05040100u);
                uint p1 = __builtin_amdgcn_perm(a1[j], a0[j], 0x07060302u);
                uint r0 = __builtin_amdgcn_perm(a3[j], a2[j], 0x05040100u);
                uint r1 = __builtin_amdgcn_perm(a3[j], a2[j], 0x07060302u);
                acc[2*j]   = __builtin_amdgcn_fdot2(__builtin_bit_cast(half2_t, p0), w01,
                             __builtin_amdgcn_fdot2(__builtin_bit_cast(half2_t, r0), w23, acc[2*j],   false), false);
                acc[2*j+1] = __builtin_amdgcn_fdot2(__builtin_bit_cast(half2_t, p1), w01,
                             __builtin_amdgcn_fdot2(__builtin_bit_cast(half2_t, r1), w23, acc[2*j+1], false), false);
            }
#else
            const __half2* pa = reinterpret_cast<const __half2*>(&h0);
            const __half2* pb = reinterpret_cast<const __half2*>(&h1);
            const __half2* pc = reinterpret_cast<const __half2*>(&h2);
            const __half2* pd_ = reinterpret_cast<const __half2*>(&h3);
            #pragma unroll
            for (int j = 0; j < 4; ++j) {
                float2 fa = __half22float2(pa[j]);
                float2 fb = __half22float2(pb[j]);
                float2 fc = __half22float2(pc[j]);
                float2 fd = __half22float2(pd_[j]);
                acc[2*j]   += w[0] * fa.x + w[1] * fb.x + w[2] * fc.x + w[3] * fd.x;
                acc[2*j+1] += w[0] * fa.y + w[1] * fb.y + w[2] * fc.y + w[3] * fd.y;
            }
#endif
        }
    }
    #pragma unroll
    for (int j = 0; j < 8; ++j) acc[j] += __shfl_xor(acc[j], 16);
    den += __shfl_xor(den, 16);
    #pragma unroll
    for (int j = 0; j < 8; ++j) acc[j] += __shfl_xor(acc[j], 32);
    den += __shfl_xor(den, 32);
    if (q == 0) {
        float inv = den > 0.f ? 1.f / den : 0.f;
        float4 b0 = *reinterpret_cast<const float4*>(bias + sub * 8);
        float4 b1 = *reinterpret_cast<const float4*>(bias + sub * 8 + 4);
        float o[8];
        o[0] = acc[0]*inv + b0.x; o[1] = acc[1]*inv + b0.y;
        o[2] = acc[2]*inv + b0.z; o[3] = acc[3]*inv + b0.w;
        o[4] = acc[4]*inv + b1.x; o[5] = acc[5]*inv + b1.y;
        o[6] = acc[6]*inv + b1.z; o[7] = acc[7]*inv + b1.w;
        if (mode) {
            uint4 u;
            __half2* up = reinterpret_cast<__half2*>(&u);
            #pragma unroll
            for (int j = 0; j < 4; ++j)
                up[j] = __floats2half2_rn(fmaxf(o[2*j], 0.f), fmaxf(o[2*j+1], 0.f));
            *reinterpret_cast<uint4*>(OUTH + (size_t)wid * 128 + sub * 8) = u;
        } else {
            *reinterpret_cast<float4*>(OUTF + (size_t)wid * 128 + sub * 8) =
                make_float4(o[0], o[1], o[2], o[3]);
            *reinterpret_cast<float4*>(OUTF + (size_t)wid * 128 + sub * 8 + 4) =
                make_float4(o[4], o[5], o[6], o[7]);
        }
    }
}

// ---------------------------------------------------------------------------
extern "C" void kernel_launch(void* const* d_in, const int* in_sizes, int n_in,
                              void* d_out, int out_size, void* d_ws, size_t ws_size,
                              hipStream_t stream) {
    const float* x        = (const float*)d_in[0];
    const int*   edge     = (const int*)d_in[1];
    const float* W0       = (const float*)d_in[2];
    const float* att_src0 = (const float*)d_in[3];
    const float* att_dst0 = (const float*)d_in[4];
    const float* b0       = (const float*)d_in[5];
    const float* W1       = (const float*)d_in[6];
    const float* att_src1 = (const float*)d_in[7];
    const float* att_dst1 = (const float*)d_in[8];
    const float* b1       = (const float*)d_in[9];
    const int* src = edge;
    const int* dst = edge + N_EDGES;
    float* out = (float*)d_out;

    char* ws = (char*)d_ws;
    size_t o = 0;
    auto alloc = [&](size_t bytes) { char* p = ws + o; o += (bytes + 255) & ~(size_t)255; return p; };
    __half* H16   = (__half*)alloc((size_t)N_NODES * 128 * 2);    // 12.8 MB (persistent)
    float* asb    = (float*)alloc((size_t)N_NODES * 4 * 4);
    float* adb    = (float*)alloc((size_t)N_NODES * 4 * 4);
    int*   off    = (int*)alloc((size_t)(N_NODES + 1) * 4);
    int*   sorted = (int*)alloc((size_t)N_EDGES * 4);             // 6.4 MB (persistent)
    // overlay: sort temps, later reused as the f16 layer-0 output
    size_t mark = o;
    int*   btot2    = (int*)alloc((size_t)2 * NB * 4);            // btotal | bcursor
    int*   bucketed = (int*)alloc((size_t)N_EDGES * 4);           // 6.4 MB
    __half* h1_16 = (__half*)(ws + mark);                         // 12.8 MB, aliases temps
    int* btotal  = btot2;
    int* bcursor = btot2 + NB;

    int agg_blocks = N_NODES / 4;   // 12500, exact

    // ---- zero bucket totals/cursors, then layer-0 GEMM fused with hist ----
    hipMemsetAsync(btot2, 0, (size_t)2 * NB * 4, stream);
    gemm_mfma<<<GEMM_BLOCKS + NBLK, 256, 0, stream>>>(x, (const __half*)nullptr, 0,
                                                      W0, att_src0, att_dst0,
                                                      H16, asb, adb, N_NODES, dst, btotal);
    // ---- sort chain (no global scan kernel) ----
    bucket_scatter<<<NBLK, 1024, 0, stream>>>(src, dst, btotal, bcursor, bucketed);
    bucket_sort<<<NB, 1024, 0, stream>>>(bucketed, btotal, sorted, off);

    // ---- layer 0 aggregate (writes f16 + relu) ----
    gat_aggregate_v3<<<agg_blocks, 256, 0, stream>>>(H16, off, sorted, asb, adb, b0,
                                                     (float*)nullptr, h1_16, N_NODES, 1);

    // ---- layer 1 ----
    gemm_mfma<<<GEMM_BLOCKS, 256, 0, stream>>>((const float*)nullptr, h1_16, 1,
                                               W1, att_src1, att_dst1,
                                               H16, asb, adb, N_NODES,
                                               (const int*)nullptr, (int*)nullptr);
    gat_aggregate_v3<<<agg_blocks, 256, 0, stream>>>(H16, off, sorted, asb, adb, b1,
                                                     out, (__half*)nullptr, N_NODES, 0);
}